// Round 1
// baseline (540.454 us; speedup 1.0000x reference)
//
#include <hip/hip_runtime.h>

// ---------------------------------------------------------------------------
// GCN: out = A*( relu(A*( relu(A*(X W1)+b1 ) W2)+b2 ) W3 ) + b3
// where A is the 800k-edge weighted adjacency (COO). We reorder (A h) W ->
// A (h W) so bias/relu fuse into the SpMM epilogue and SpMM3 runs at d=64.
// Per launch: build CSR (hist -> scan -> scatter), then 3x {GEMM, SpMM}.
// ---------------------------------------------------------------------------

__global__ void hist_kernel(const int* __restrict__ rows, int* __restrict__ cnt, int e) {
    int i = blockIdx.x * blockDim.x + threadIdx.x;
    if (i < e) atomicAdd(&cnt[rows[i]], 1);
}

// Single-block exclusive scan over n counts (counts aliases cursor buffer).
__global__ void scan_kernel(const int* __restrict__ counts, int* __restrict__ row_ptr,
                            int* __restrict__ cursor, int n) {
    __shared__ int part[1024];
    const int t = threadIdx.x;
    const int chunk = (n + 1023) / 1024;
    const int start = t * chunk;
    const int end = min(start + chunk, n);
    int s = 0;
    for (int i = start; i < end; i++) s += counts[i];
    part[t] = s;
    __syncthreads();
    // Hillis-Steele inclusive scan over 1024 partials
    for (int off = 1; off < 1024; off <<= 1) {
        int v = (t >= off) ? part[t - off] : 0;
        __syncthreads();
        part[t] += v;
        __syncthreads();
    }
    int run = (t == 0) ? 0 : part[t - 1];
    for (int i = start; i < end; i++) {
        int c = counts[i];          // read BEFORE cursor overwrite (same buffer ok: own chunk)
        row_ptr[i] = run;
        cursor[i]  = run;
        run += c;
    }
    if (t == 1023) row_ptr[n] = run;   // == E
}

__global__ void scatter_kernel(const int* __restrict__ rows, const int* __restrict__ cols,
                               const float* __restrict__ w, int* __restrict__ cursor,
                               int* __restrict__ scol, float* __restrict__ sw, int e) {
    int i = blockIdx.x * blockDim.x + threadIdx.x;
    if (i < e) {
        int r = rows[i];
        int p = atomicAdd(&cursor[r], 1);
        scol[p] = cols[i];
        sw[p]   = w[i];
    }
}

// C[n,BN] = A[n,128] @ B[128,BN], fp32, LDS tiled. 256 threads, BM=64.
template <int BN, int TN>
__global__ __launch_bounds__(256) void gemm_kernel(const float* __restrict__ A,
                                                   const float* __restrict__ B,
                                                   float* __restrict__ C, int n) {
    constexpr int BM = 64, BK = 16, K = 128;
    __shared__ float As[BM][BK];
    __shared__ float Bs[BK][BN];
    const int tid = threadIdx.x;
    const int tr = tid >> 5;    // 0..7
    const int tc = tid & 31;    // 0..31
    const int block_row = blockIdx.x * BM;

    float acc[8][TN];
#pragma unroll
    for (int m = 0; m < 8; m++)
#pragma unroll
        for (int j = 0; j < TN; j++) acc[m][j] = 0.f;

    for (int k0 = 0; k0 < K; k0 += BK) {
        // load A tile 64x16 (float4 per thread)
        {
            int lr = tid >> 2;
            int lk = (tid & 3) << 2;
            int gr = block_row + lr;
            float4 av = make_float4(0.f, 0.f, 0.f, 0.f);
            if (gr < n) av = *reinterpret_cast<const float4*>(&A[(size_t)gr * K + k0 + lk]);
            *reinterpret_cast<float4*>(&As[lr][lk]) = av;
        }
        // load B tile 16xBN
#pragma unroll
        for (int i = 0; i < BN / 64; i++) {
            int idx = tid * (BN / 64) + i;
            int br = idx / (BN / 4);
            int bc = (idx % (BN / 4)) << 2;
            *reinterpret_cast<float4*>(&Bs[br][bc]) =
                *reinterpret_cast<const float4*>(&B[(size_t)(k0 + br) * BN + bc]);
        }
        __syncthreads();
#pragma unroll
        for (int kk = 0; kk < BK; kk++) {
            float a[8];
#pragma unroll
            for (int m = 0; m < 8; m++) a[m] = As[tr * 8 + m][kk];
            float b[TN];
            if constexpr (TN == 4) {
                float4 bv = *reinterpret_cast<const float4*>(&Bs[kk][tc * 4]);
                b[0] = bv.x; b[1] = bv.y; b[2] = bv.z; b[3] = bv.w;
            } else {
                float2 bv = *reinterpret_cast<const float2*>(&Bs[kk][tc * 2]);
                b[0] = bv.x; b[1] = bv.y;
            }
#pragma unroll
            for (int m = 0; m < 8; m++)
#pragma unroll
                for (int j = 0; j < TN; j++) acc[m][j] = fmaf(a[m], b[j], acc[m][j]);
        }
        __syncthreads();
    }
#pragma unroll
    for (int m = 0; m < 8; m++) {
        int gr = block_row + tr * 8 + m;
        if (gr < n) {
            if constexpr (TN == 4) {
                float4 v = make_float4(acc[m][0], acc[m][1], acc[m][2], acc[m][3]);
                *reinterpret_cast<float4*>(&C[(size_t)gr * BN + tc * 4]) = v;
            } else {
                float2 v = make_float2(acc[m][0], acc[m][1]);
                *reinterpret_cast<float2*>(&C[(size_t)gr * BN + tc * 2]) = v;
            }
        }
    }
}

// out[row,:] = (sum_k w_k * Z[col_k,:]) + bias, optional relu. One wave/row.
template <int D, bool RELU>
__global__ __launch_bounds__(256) void spmm_kernel(const int* __restrict__ row_ptr,
                                                   const int* __restrict__ scol,
                                                   const float* __restrict__ sw,
                                                   const float* __restrict__ Z,
                                                   const float* __restrict__ bias,
                                                   float* __restrict__ out, int n) {
    int gtid = blockIdx.x * blockDim.x + threadIdx.x;
    int row = gtid >> 6;
    int lane = threadIdx.x & 63;
    if (row >= n) return;
    int beg = row_ptr[row], end = row_ptr[row + 1];
    if constexpr (D == 128) {
        int j = lane << 1;
        float ax = 0.f, ay = 0.f;
        for (int k = beg; k < end; k++) {
            int c = scol[k];
            float w = sw[k];
            float2 z = *reinterpret_cast<const float2*>(&Z[(size_t)c * 128 + j]);
            ax = fmaf(w, z.x, ax);
            ay = fmaf(w, z.y, ay);
        }
        ax += bias[j];
        ay += bias[j + 1];
        if constexpr (RELU) { ax = fmaxf(ax, 0.f); ay = fmaxf(ay, 0.f); }
        *reinterpret_cast<float2*>(&out[(size_t)row * 128 + j]) = make_float2(ax, ay);
    } else {
        float a = 0.f;
        for (int k = beg; k < end; k++)
            a = fmaf(sw[k], Z[(size_t)scol[k] * D + lane], a);
        a += bias[lane];
        if constexpr (RELU) a = fmaxf(a, 0.f);
        out[(size_t)row * D + lane] = a;
    }
}

extern "C" void kernel_launch(void* const* d_in, const int* in_sizes, int n_in,
                              void* d_out, int out_size, void* d_ws, size_t ws_size,
                              hipStream_t stream) {
    const float* X    = (const float*)d_in[0];
    const int*   erow = (const int*)d_in[1];
    const int*   ecol = (const int*)d_in[2];
    const float* ew   = (const float*)d_in[3];
    const float* W1   = (const float*)d_in[4];
    const float* b1   = (const float*)d_in[5];
    const float* W2   = (const float*)d_in[6];
    const float* b2   = (const float*)d_in[7];
    const float* W3   = (const float*)d_in[8];
    const float* b3   = (const float*)d_in[9];
    float* out = (float*)d_out;

    const int n = in_sizes[0] / 128;   // 50000
    const int e = in_sizes[1];         // 800000

    // workspace carve-up (256B aligned)
    char* p = (char*)d_ws;
    auto alloc = [&](size_t bytes) {
        void* r = (void*)p;
        p += (bytes + 255) & ~(size_t)255;
        return r;
    };
    int*   row_ptr = (int*)alloc((size_t)(n + 1) * sizeof(int));
    int*   cursor  = (int*)alloc((size_t)n * sizeof(int));
    int*   scol    = (int*)alloc((size_t)e * sizeof(int));
    float* sw      = (float*)alloc((size_t)e * sizeof(float));
    float* Z       = (float*)alloc((size_t)n * 128 * sizeof(float));
    float* H       = (float*)alloc((size_t)n * 128 * sizeof(float));

    const int eb = (e + 255) / 256;
    const int gemm_grid = (n + 63) / 64;
    const int spmm_grid = (n + 3) / 4;   // 4 waves/block, 1 row/wave

    // ---- CSR build ----
    hipMemsetAsync(cursor, 0, (size_t)n * sizeof(int), stream);
    hist_kernel<<<eb, 256, 0, stream>>>(erow, cursor, e);
    scan_kernel<<<1, 1024, 0, stream>>>(cursor, row_ptr, cursor, n);
    scatter_kernel<<<eb, 256, 0, stream>>>(erow, ecol, ew, cursor, scol, sw, e);

    // ---- layer 1: Z = X @ W1 ; H = relu(A Z + b1) ----
    gemm_kernel<128, 4><<<gemm_grid, 256, 0, stream>>>(X, W1, Z, n);
    spmm_kernel<128, true><<<spmm_grid, 256, 0, stream>>>(row_ptr, scol, sw, Z, b1, H, n);

    // ---- layer 2 ----
    gemm_kernel<128, 4><<<gemm_grid, 256, 0, stream>>>(H, W2, Z, n);
    spmm_kernel<128, true><<<spmm_grid, 256, 0, stream>>>(row_ptr, scol, sw, Z, b2, H, n);

    // ---- layer 3: Z3 = H @ W3 (n x 64) ; out = A Z3 + b3 ----
    gemm_kernel<64, 2><<<gemm_grid, 256, 0, stream>>>(H, W3, Z, n);
    spmm_kernel<64, false><<<spmm_grid, 256, 0, stream>>>(row_ptr, scol, sw, Z, b3, out, n);
}

// Round 2
// 428.338 us; speedup vs baseline: 1.2617x; 1.2617x over previous
//
#include <hip/hip_runtime.h>

// ---------------------------------------------------------------------------
// GCN: out = A*( relu(A*( relu(A*(X W1)+b1 ) W2)+b2 ) W3 ) + b3
// A = 800k-edge weighted adjacency (COO). Reordered (A h) W -> A (h W) so
// bias/relu fuse into SpMM epilogue and SpMM3 runs at d=64.
// Per launch: CSR build (hist -> hierarchical scan -> scatter), 3x {GEMM, SpMM}.
// R1: replaced 112us single-block chunked scan (uncoalesced, 1 CU) with a
//     3-kernel hierarchical scan (coalesced int4, ~49 blocks). Expect <10us.
// ---------------------------------------------------------------------------

__global__ void hist_kernel(const int* __restrict__ rows, int* __restrict__ cnt, int e) {
    int i = blockIdx.x * blockDim.x + threadIdx.x;
    if (i < e) atomicAdd(&cnt[rows[i]], 1);
}

// A: per-block (1024 elements) partial sums, coalesced int4 loads.
__global__ __launch_bounds__(256) void partial_sum_kernel(const int* __restrict__ counts,
                                                          int* __restrict__ partials, int n) {
    int base = blockIdx.x * 1024 + threadIdx.x * 4;
    int s = 0;
    if (base + 3 < n) {
        int4 v = *reinterpret_cast<const int4*>(&counts[base]);
        s = v.x + v.y + v.z + v.w;
    } else {
        for (int i = base; i < n && i < base + 4; i++) s += counts[i];
    }
#pragma unroll
    for (int off = 32; off; off >>= 1) s += __shfl_down(s, off, 64);
    __shared__ int red[4];
    int wave = threadIdx.x >> 6;
    if ((threadIdx.x & 63) == 0) red[wave] = s;
    __syncthreads();
    if (threadIdx.x == 0) partials[blockIdx.x] = red[0] + red[1] + red[2] + red[3];
}

// B: single-block scan of the ~49 block partials; also writes row_ptr[n] = E.
__global__ __launch_bounds__(1024) void partial_scan_kernel(int* __restrict__ partials,
                                                            int* __restrict__ row_ptr,
                                                            int nb, int n) {
    __shared__ int sm[1024];
    int t = threadIdx.x;
    int v = (t < nb) ? partials[t] : 0;
    sm[t] = v;
    __syncthreads();
    for (int off = 1; off < 1024; off <<= 1) {
        int u = (t >= off) ? sm[t - off] : 0;
        __syncthreads();
        sm[t] += u;
        __syncthreads();
    }
    if (t < nb) partials[t] = sm[t] - v;      // exclusive block offset
    if (t == 0) row_ptr[n] = sm[1023];        // total == E
}

// C: re-read counts coalesced, block-scan thread sums, emit row_ptr/cursor int4.
// NOTE: cursor aliases counts — each element is read (into regs) by the same
// thread that writes it, so the in-place overwrite is safe.
__global__ __launch_bounds__(256) void scan_scatter_kernel(const int* __restrict__ counts,
                                                           const int* __restrict__ partials,
                                                           int* __restrict__ row_ptr,
                                                           int* __restrict__ cursor, int n) {
    int t = threadIdx.x;
    int base = blockIdx.x * 1024 + t * 4;
    int c[4];
    int s = 0;
#pragma unroll
    for (int j = 0; j < 4; j++) {
        int i = base + j;
        c[j] = (i < n) ? counts[i] : 0;
        s += c[j];
    }
    __shared__ int sm[256];
    sm[t] = s;
    __syncthreads();
    for (int off = 1; off < 256; off <<= 1) {
        int u = (t >= off) ? sm[t - off] : 0;
        __syncthreads();
        sm[t] += u;
        __syncthreads();
    }
    int run = partials[blockIdx.x] + sm[t] - s;   // exclusive prefix for this thread
    int r0 = run, r1 = r0 + c[0], r2 = r1 + c[1], r3 = r2 + c[2];
    if (base + 3 < n) {
        int4 rp = make_int4(r0, r1, r2, r3);
        *reinterpret_cast<int4*>(&row_ptr[base]) = rp;
        *reinterpret_cast<int4*>(&cursor[base])  = rp;
    } else {
        int rr[4] = {r0, r1, r2, r3};
        for (int j = 0; j < 4; j++) {
            int i = base + j;
            if (i < n) { row_ptr[i] = rr[j]; cursor[i] = rr[j]; }
        }
    }
}

__global__ void scatter_kernel(const int* __restrict__ rows, const int* __restrict__ cols,
                               const float* __restrict__ w, int* __restrict__ cursor,
                               int* __restrict__ scol, float* __restrict__ sw, int e) {
    int i = blockIdx.x * blockDim.x + threadIdx.x;
    if (i < e) {
        int r = rows[i];
        int p = atomicAdd(&cursor[r], 1);
        scol[p] = cols[i];
        sw[p]   = w[i];
    }
}

// C[n,BN] = A[n,128] @ B[128,BN], fp32, LDS tiled. 256 threads, BM=64.
template <int BN, int TN>
__global__ __launch_bounds__(256) void gemm_kernel(const float* __restrict__ A,
                                                   const float* __restrict__ B,
                                                   float* __restrict__ C, int n) {
    constexpr int BM = 64, BK = 16, K = 128;
    __shared__ float As[BM][BK];
    __shared__ float Bs[BK][BN];
    const int tid = threadIdx.x;
    const int tr = tid >> 5;    // 0..7
    const int tc = tid & 31;    // 0..31
    const int block_row = blockIdx.x * BM;

    float acc[8][TN];
#pragma unroll
    for (int m = 0; m < 8; m++)
#pragma unroll
        for (int j = 0; j < TN; j++) acc[m][j] = 0.f;

    for (int k0 = 0; k0 < K; k0 += BK) {
        {
            int lr = tid >> 2;
            int lk = (tid & 3) << 2;
            int gr = block_row + lr;
            float4 av = make_float4(0.f, 0.f, 0.f, 0.f);
            if (gr < n) av = *reinterpret_cast<const float4*>(&A[(size_t)gr * K + k0 + lk]);
            *reinterpret_cast<float4*>(&As[lr][lk]) = av;
        }
#pragma unroll
        for (int i = 0; i < BN / 64; i++) {
            int idx = tid * (BN / 64) + i;
            int br = idx / (BN / 4);
            int bc = (idx % (BN / 4)) << 2;
            *reinterpret_cast<float4*>(&Bs[br][bc]) =
                *reinterpret_cast<const float4*>(&B[(size_t)(k0 + br) * BN + bc]);
        }
        __syncthreads();
#pragma unroll
        for (int kk = 0; kk < BK; kk++) {
            float a[8];
#pragma unroll
            for (int m = 0; m < 8; m++) a[m] = As[tr * 8 + m][kk];
            float b[TN];
            if constexpr (TN == 4) {
                float4 bv = *reinterpret_cast<const float4*>(&Bs[kk][tc * 4]);
                b[0] = bv.x; b[1] = bv.y; b[2] = bv.z; b[3] = bv.w;
            } else {
                float2 bv = *reinterpret_cast<const float2*>(&Bs[kk][tc * 2]);
                b[0] = bv.x; b[1] = bv.y;
            }
#pragma unroll
            for (int m = 0; m < 8; m++)
#pragma unroll
                for (int j = 0; j < TN; j++) acc[m][j] = fmaf(a[m], b[j], acc[m][j]);
        }
        __syncthreads();
    }
#pragma unroll
    for (int m = 0; m < 8; m++) {
        int gr = block_row + tr * 8 + m;
        if (gr < n) {
            if constexpr (TN == 4) {
                float4 v = make_float4(acc[m][0], acc[m][1], acc[m][2], acc[m][3]);
                *reinterpret_cast<float4*>(&C[(size_t)gr * BN + tc * 4]) = v;
            } else {
                float2 v = make_float2(acc[m][0], acc[m][1]);
                *reinterpret_cast<float2*>(&C[(size_t)gr * BN + tc * 2]) = v;
            }
        }
    }
}

// out[row,:] = (sum_k w_k * Z[col_k,:]) + bias, optional relu. One wave/row.
template <int D, bool RELU>
__global__ __launch_bounds__(256) void spmm_kernel(const int* __restrict__ row_ptr,
                                                   const int* __restrict__ scol,
                                                   const float* __restrict__ sw,
                                                   const float* __restrict__ Z,
                                                   const float* __restrict__ bias,
                                                   float* __restrict__ out, int n) {
    int gtid = blockIdx.x * blockDim.x + threadIdx.x;
    int row = gtid >> 6;
    int lane = threadIdx.x & 63;
    if (row >= n) return;
    int beg = row_ptr[row], end = row_ptr[row + 1];
    if constexpr (D == 128) {
        int j = lane << 1;
        float ax = 0.f, ay = 0.f;
        for (int k = beg; k < end; k++) {
            int c = scol[k];
            float w = sw[k];
            float2 z = *reinterpret_cast<const float2*>(&Z[(size_t)c * 128 + j]);
            ax = fmaf(w, z.x, ax);
            ay = fmaf(w, z.y, ay);
        }
        ax += bias[j];
        ay += bias[j + 1];
        if constexpr (RELU) { ax = fmaxf(ax, 0.f); ay = fmaxf(ay, 0.f); }
        *reinterpret_cast<float2*>(&out[(size_t)row * 128 + j]) = make_float2(ax, ay);
    } else {
        float a = 0.f;
        for (int k = beg; k < end; k++)
            a = fmaf(sw[k], Z[(size_t)scol[k] * D + lane], a);
        a += bias[lane];
        if constexpr (RELU) a = fmaxf(a, 0.f);
        out[(size_t)row * D + lane] = a;
    }
}

extern "C" void kernel_launch(void* const* d_in, const int* in_sizes, int n_in,
                              void* d_out, int out_size, void* d_ws, size_t ws_size,
                              hipStream_t stream) {
    const float* X    = (const float*)d_in[0];
    const int*   erow = (const int*)d_in[1];
    const int*   ecol = (const int*)d_in[2];
    const float* ew   = (const float*)d_in[3];
    const float* W1   = (const float*)d_in[4];
    const float* b1   = (const float*)d_in[5];
    const float* W2   = (const float*)d_in[6];
    const float* b2   = (const float*)d_in[7];
    const float* W3   = (const float*)d_in[8];
    const float* b3   = (const float*)d_in[9];
    float* out = (float*)d_out;

    const int n = in_sizes[0] / 128;   // 50000
    const int e = in_sizes[1];         // 800000

    char* p = (char*)d_ws;
    auto alloc = [&](size_t bytes) {
        void* r = (void*)p;
        p += (bytes + 255) & ~(size_t)255;
        return r;
    };
    int*   row_ptr  = (int*)alloc((size_t)(n + 1) * sizeof(int));
    int*   cursor   = (int*)alloc((size_t)n * sizeof(int));
    int*   partials = (int*)alloc(4096 * sizeof(int));
    int*   scol     = (int*)alloc((size_t)e * sizeof(int));
    float* sw       = (float*)alloc((size_t)e * sizeof(float));
    float* Z        = (float*)alloc((size_t)n * 128 * sizeof(float));
    float* H        = (float*)alloc((size_t)n * 128 * sizeof(float));

    const int eb = (e + 255) / 256;
    const int nb = (n + 1023) / 1024;            // scan blocks (49)
    const int gemm_grid = (n + 63) / 64;
    const int spmm_grid = (n + 3) / 4;           // 4 waves/block, 1 row/wave

    // ---- CSR build ----
    hipMemsetAsync(cursor, 0, (size_t)n * sizeof(int), stream);
    hist_kernel<<<eb, 256, 0, stream>>>(erow, cursor, e);
    partial_sum_kernel<<<nb, 256, 0, stream>>>(cursor, partials, n);
    partial_scan_kernel<<<1, 1024, 0, stream>>>(partials, row_ptr, nb, n);
    scan_scatter_kernel<<<nb, 256, 0, stream>>>(cursor, partials, row_ptr, cursor, n);
    scatter_kernel<<<eb, 256, 0, stream>>>(erow, ecol, ew, cursor, scol, sw, e);

    // ---- layer 1: Z = X @ W1 ; H = relu(A Z + b1) ----
    gemm_kernel<128, 4><<<gemm_grid, 256, 0, stream>>>(X, W1, Z, n);
    spmm_kernel<128, true><<<spmm_grid, 256, 0, stream>>>(row_ptr, scol, sw, Z, b1, H, n);

    // ---- layer 2 ----
    gemm_kernel<128, 4><<<gemm_grid, 256, 0, stream>>>(H, W2, Z, n);
    spmm_kernel<128, true><<<spmm_grid, 256, 0, stream>>>(row_ptr, scol, sw, Z, b2, H, n);

    // ---- layer 3: Z3 = H @ W3 (n x 64) ; out = A Z3 + b3 ----
    gemm_kernel<64, 2><<<gemm_grid, 256, 0, stream>>>(H, W3, Z, n);
    spmm_kernel<64, false><<<spmm_grid, 256, 0, stream>>>(row_ptr, scol, sw, Z, b3, out, n);
}

// Round 3
// 414.059 us; speedup vs baseline: 1.3053x; 1.0345x over previous
//
#include <hip/hip_runtime.h>

// ---------------------------------------------------------------------------
// GCN: out = A*( relu(A*( relu(A*(X W1)+b1 ) W2)+b2 ) W3 ) + b3
// Reordered (A h) W -> A (h W). CSR build + 3x {GEMM, SpMM}.
// R1: hierarchical scan (coalesced) replaced 112us single-block scan.
// R2: SpMM gather operand Z stored as bf16 (GEMM epilogue converts).
//     Halves the random-gather traffic (the measured bottleneck: 177MB
//     FETCH/dispatch, 88us) and doubles L2 residency. fp32 accumulate.
// ---------------------------------------------------------------------------

typedef unsigned int uint32;
typedef unsigned short ushort16;

static __device__ __forceinline__ unsigned short f2bf(float x) {
    unsigned int u = __builtin_bit_cast(unsigned int, x);
    u += 0x7FFFu + ((u >> 16) & 1u);   // round-to-nearest-even
    return (unsigned short)(u >> 16);
}

__global__ void hist_kernel(const int* __restrict__ rows, int* __restrict__ cnt, int e) {
    int i = blockIdx.x * blockDim.x + threadIdx.x;
    if (i < e) atomicAdd(&cnt[rows[i]], 1);
}

__global__ __launch_bounds__(256) void partial_sum_kernel(const int* __restrict__ counts,
                                                          int* __restrict__ partials, int n) {
    int base = blockIdx.x * 1024 + threadIdx.x * 4;
    int s = 0;
    if (base + 3 < n) {
        int4 v = *reinterpret_cast<const int4*>(&counts[base]);
        s = v.x + v.y + v.z + v.w;
    } else {
        for (int i = base; i < n && i < base + 4; i++) s += counts[i];
    }
#pragma unroll
    for (int off = 32; off; off >>= 1) s += __shfl_down(s, off, 64);
    __shared__ int red[4];
    int wave = threadIdx.x >> 6;
    if ((threadIdx.x & 63) == 0) red[wave] = s;
    __syncthreads();
    if (threadIdx.x == 0) partials[blockIdx.x] = red[0] + red[1] + red[2] + red[3];
}

__global__ __launch_bounds__(1024) void partial_scan_kernel(int* __restrict__ partials,
                                                            int* __restrict__ row_ptr,
                                                            int nb, int n) {
    __shared__ int sm[1024];
    int t = threadIdx.x;
    int v = (t < nb) ? partials[t] : 0;
    sm[t] = v;
    __syncthreads();
    for (int off = 1; off < 1024; off <<= 1) {
        int u = (t >= off) ? sm[t - off] : 0;
        __syncthreads();
        sm[t] += u;
        __syncthreads();
    }
    if (t < nb) partials[t] = sm[t] - v;
    if (t == 0) row_ptr[n] = sm[1023];
}

__global__ __launch_bounds__(256) void scan_scatter_kernel(const int* __restrict__ counts,
                                                           const int* __restrict__ partials,
                                                           int* __restrict__ row_ptr,
                                                           int* __restrict__ cursor, int n) {
    int t = threadIdx.x;
    int base = blockIdx.x * 1024 + t * 4;
    int c[4];
    int s = 0;
#pragma unroll
    for (int j = 0; j < 4; j++) {
        int i = base + j;
        c[j] = (i < n) ? counts[i] : 0;
        s += c[j];
    }
    __shared__ int sm[256];
    sm[t] = s;
    __syncthreads();
    for (int off = 1; off < 256; off <<= 1) {
        int u = (t >= off) ? sm[t - off] : 0;
        __syncthreads();
        sm[t] += u;
        __syncthreads();
    }
    int run = partials[blockIdx.x] + sm[t] - s;
    int r0 = run, r1 = r0 + c[0], r2 = r1 + c[1], r3 = r2 + c[2];
    if (base + 3 < n) {
        int4 rp = make_int4(r0, r1, r2, r3);
        *reinterpret_cast<int4*>(&row_ptr[base]) = rp;
        *reinterpret_cast<int4*>(&cursor[base])  = rp;
    } else {
        int rr[4] = {r0, r1, r2, r3};
        for (int j = 0; j < 4; j++) {
            int i = base + j;
            if (i < n) { row_ptr[i] = rr[j]; cursor[i] = rr[j]; }
        }
    }
}

__global__ void scatter_kernel(const int* __restrict__ rows, const int* __restrict__ cols,
                               const float* __restrict__ w, int* __restrict__ cursor,
                               int* __restrict__ scol, float* __restrict__ sw, int e) {
    int i = blockIdx.x * blockDim.x + threadIdx.x;
    if (i < e) {
        int r = rows[i];
        int p = atomicAdd(&cursor[r], 1);
        scol[p] = cols[i];
        sw[p]   = w[i];
    }
}

// C[n,BN](bf16) = A[n,128](f32) @ B[128,BN](f32). 256 threads, BM=64.
template <int BN, int TN>
__global__ __launch_bounds__(256) void gemm_kernel(const float* __restrict__ A,
                                                   const float* __restrict__ B,
                                                   unsigned short* __restrict__ C, int n) {
    constexpr int BM = 64, BK = 16, K = 128;
    __shared__ float As[BM][BK];
    __shared__ float Bs[BK][BN];
    const int tid = threadIdx.x;
    const int tr = tid >> 5;
    const int tc = tid & 31;
    const int block_row = blockIdx.x * BM;

    float acc[8][TN];
#pragma unroll
    for (int m = 0; m < 8; m++)
#pragma unroll
        for (int j = 0; j < TN; j++) acc[m][j] = 0.f;

    for (int k0 = 0; k0 < K; k0 += BK) {
        {
            int lr = tid >> 2;
            int lk = (tid & 3) << 2;
            int gr = block_row + lr;
            float4 av = make_float4(0.f, 0.f, 0.f, 0.f);
            if (gr < n) av = *reinterpret_cast<const float4*>(&A[(size_t)gr * K + k0 + lk]);
            *reinterpret_cast<float4*>(&As[lr][lk]) = av;
        }
#pragma unroll
        for (int i = 0; i < BN / 64; i++) {
            int idx = tid * (BN / 64) + i;
            int br = idx / (BN / 4);
            int bc = (idx % (BN / 4)) << 2;
            *reinterpret_cast<float4*>(&Bs[br][bc]) =
                *reinterpret_cast<const float4*>(&B[(size_t)(k0 + br) * BN + bc]);
        }
        __syncthreads();
#pragma unroll
        for (int kk = 0; kk < BK; kk++) {
            float a[8];
#pragma unroll
            for (int m = 0; m < 8; m++) a[m] = As[tr * 8 + m][kk];
            float b[TN];
            if constexpr (TN == 4) {
                float4 bv = *reinterpret_cast<const float4*>(&Bs[kk][tc * 4]);
                b[0] = bv.x; b[1] = bv.y; b[2] = bv.z; b[3] = bv.w;
            } else {
                float2 bv = *reinterpret_cast<const float2*>(&Bs[kk][tc * 2]);
                b[0] = bv.x; b[1] = bv.y;
            }
#pragma unroll
            for (int m = 0; m < 8; m++)
#pragma unroll
                for (int j = 0; j < TN; j++) acc[m][j] = fmaf(a[m], b[j], acc[m][j]);
        }
        __syncthreads();
    }
#pragma unroll
    for (int m = 0; m < 8; m++) {
        int gr = block_row + tr * 8 + m;
        if (gr < n) {
            if constexpr (TN == 4) {
                ushort4 v;
                v.x = f2bf(acc[m][0]); v.y = f2bf(acc[m][1]);
                v.z = f2bf(acc[m][2]); v.w = f2bf(acc[m][3]);
                *reinterpret_cast<ushort4*>(&C[(size_t)gr * BN + tc * 4]) = v;
            } else {
                uint32 v = (uint32)f2bf(acc[m][0]) | ((uint32)f2bf(acc[m][1]) << 16);
                *reinterpret_cast<uint32*>(&C[(size_t)gr * BN + tc * 2]) = v;
            }
        }
    }
}

// out[row,:] = (sum_k w_k * Zb[col_k,:]) + bias (Zb bf16, fp32 accum).
template <int D, bool RELU>
__global__ __launch_bounds__(256) void spmm_kernel(const int* __restrict__ row_ptr,
                                                   const int* __restrict__ scol,
                                                   const float* __restrict__ sw,
                                                   const unsigned short* __restrict__ Zb,
                                                   const float* __restrict__ bias,
                                                   float* __restrict__ out, int n) {
    int gtid = blockIdx.x * blockDim.x + threadIdx.x;
    int row = gtid >> 6;
    int lane = threadIdx.x & 63;
    if (row >= n) return;
    int beg = row_ptr[row], end = row_ptr[row + 1];
    if constexpr (D == 128) {
        int j = lane << 1;
        float ax = 0.f, ay = 0.f;
        for (int k = beg; k < end; k++) {
            int c = scol[k];
            float w = sw[k];
            uint32 zz = *reinterpret_cast<const uint32*>(&Zb[(size_t)c * 128 + j]);
            float zlo = __builtin_bit_cast(float, zz << 16);
            float zhi = __builtin_bit_cast(float, zz & 0xFFFF0000u);
            ax = fmaf(w, zlo, ax);
            ay = fmaf(w, zhi, ay);
        }
        ax += bias[j];
        ay += bias[j + 1];
        if constexpr (RELU) { ax = fmaxf(ax, 0.f); ay = fmaxf(ay, 0.f); }
        *reinterpret_cast<float2*>(&out[(size_t)row * 128 + j]) = make_float2(ax, ay);
    } else {
        float a = 0.f;
        for (int k = beg; k < end; k++) {
            uint32 zz = (uint32)Zb[(size_t)scol[k] * D + lane];
            a = fmaf(sw[k], __builtin_bit_cast(float, zz << 16), a);
        }
        a += bias[lane];
        if constexpr (RELU) a = fmaxf(a, 0.f);
        out[(size_t)row * D + lane] = a;
    }
}

extern "C" void kernel_launch(void* const* d_in, const int* in_sizes, int n_in,
                              void* d_out, int out_size, void* d_ws, size_t ws_size,
                              hipStream_t stream) {
    const float* X    = (const float*)d_in[0];
    const int*   erow = (const int*)d_in[1];
    const int*   ecol = (const int*)d_in[2];
    const float* ew   = (const float*)d_in[3];
    const float* W1   = (const float*)d_in[4];
    const float* b1   = (const float*)d_in[5];
    const float* W2   = (const float*)d_in[6];
    const float* b2   = (const float*)d_in[7];
    const float* W3   = (const float*)d_in[8];
    const float* b3   = (const float*)d_in[9];
    float* out = (float*)d_out;

    const int n = in_sizes[0] / 128;   // 50000
    const int e = in_sizes[1];         // 800000

    char* p = (char*)d_ws;
    auto alloc = [&](size_t bytes) {
        void* r = (void*)p;
        p += (bytes + 255) & ~(size_t)255;
        return r;
    };
    int*            row_ptr  = (int*)alloc((size_t)(n + 1) * sizeof(int));
    int*            cursor   = (int*)alloc((size_t)n * sizeof(int));
    int*            partials = (int*)alloc(4096 * sizeof(int));
    int*            scol     = (int*)alloc((size_t)e * sizeof(int));
    float*          sw       = (float*)alloc((size_t)e * sizeof(float));
    unsigned short* Zb       = (unsigned short*)alloc((size_t)n * 128 * sizeof(unsigned short));
    float*          H        = (float*)alloc((size_t)n * 128 * sizeof(float));

    const int eb = (e + 255) / 256;
    const int nb = (n + 1023) / 1024;
    const int gemm_grid = (n + 63) / 64;
    const int spmm_grid = (n + 3) / 4;

    // ---- CSR build ----
    hipMemsetAsync(cursor, 0, (size_t)n * sizeof(int), stream);
    hist_kernel<<<eb, 256, 0, stream>>>(erow, cursor, e);
    partial_sum_kernel<<<nb, 256, 0, stream>>>(cursor, partials, n);
    partial_scan_kernel<<<1, 1024, 0, stream>>>(partials, row_ptr, nb, n);
    scan_scatter_kernel<<<nb, 256, 0, stream>>>(cursor, partials, row_ptr, cursor, n);
    scatter_kernel<<<eb, 256, 0, stream>>>(erow, ecol, ew, cursor, scol, sw, e);

    // ---- layer 1: Zb = bf16(X @ W1) ; H = relu(A Zb + b1) ----
    gemm_kernel<128, 4><<<gemm_grid, 256, 0, stream>>>(X, W1, Zb, n);
    spmm_kernel<128, true><<<spmm_grid, 256, 0, stream>>>(row_ptr, scol, sw, Zb, b1, H, n);

    // ---- layer 2 ----
    gemm_kernel<128, 4><<<gemm_grid, 256, 0, stream>>>(H, W2, Zb, n);
    spmm_kernel<128, true><<<spmm_grid, 256, 0, stream>>>(row_ptr, scol, sw, Zb, b2, H, n);

    // ---- layer 3: Zb = bf16(H @ W3) (n x 64) ; out = A Zb + b3 ----
    gemm_kernel<64, 2><<<gemm_grid, 256, 0, stream>>>(H, W3, Zb, n);
    spmm_kernel<64, false><<<spmm_grid, 256, 0, stream>>>(row_ptr, scol, sw, Zb, b3, out, n);
}

// Round 4
// 266.350 us; speedup vs baseline: 2.0291x; 1.5546x over previous
//
#include <hip/hip_runtime.h>

// ---------------------------------------------------------------------------
// GCN: out = A*( relu(A*( relu(A*(X W1)+b1 ) W2)+b2 ) W3 ) + b3
// Reordered (A h) W -> A (h W). CSR build + 3x {GEMM, SpMM}.
// R1: hierarchical scan (coalesced) replaced 112us single-block scan.
// R2: SpMM gather operand Z stored bf16 -> halved FETCH (177->80MB) but dur
//     88->81us only: SpMM is LATENCY-bound, not BW-bound.
// R3: SpMM restructured for MLP: 4 edge-groups x 16 lanes, 16B/lane gather
//     (4 edges / 1KB in flight per iteration, trips 16->4), shfl_xor reduce.
//     Edges packed as int2{col,w} (one 8B broadcast load per edge).
// ---------------------------------------------------------------------------

typedef unsigned int uint32;

static __device__ __forceinline__ unsigned short f2bf(float x) {
    unsigned int u = __builtin_bit_cast(unsigned int, x);
    u += 0x7FFFu + ((u >> 16) & 1u);   // round-to-nearest-even
    return (unsigned short)(u >> 16);
}
static __device__ __forceinline__ float bflo(uint32 u) {
    return __builtin_bit_cast(float, u << 16);
}
static __device__ __forceinline__ float bfhi(uint32 u) {
    return __builtin_bit_cast(float, u & 0xFFFF0000u);
}

__global__ void hist_kernel(const int* __restrict__ rows, int* __restrict__ cnt, int e) {
    int i = blockIdx.x * blockDim.x + threadIdx.x;
    if (i < e) atomicAdd(&cnt[rows[i]], 1);
}

__global__ __launch_bounds__(256) void partial_sum_kernel(const int* __restrict__ counts,
                                                          int* __restrict__ partials, int n) {
    int base = blockIdx.x * 1024 + threadIdx.x * 4;
    int s = 0;
    if (base + 3 < n) {
        int4 v = *reinterpret_cast<const int4*>(&counts[base]);
        s = v.x + v.y + v.z + v.w;
    } else {
        for (int i = base; i < n && i < base + 4; i++) s += counts[i];
    }
#pragma unroll
    for (int off = 32; off; off >>= 1) s += __shfl_down(s, off, 64);
    __shared__ int red[4];
    int wave = threadIdx.x >> 6;
    if ((threadIdx.x & 63) == 0) red[wave] = s;
    __syncthreads();
    if (threadIdx.x == 0) partials[blockIdx.x] = red[0] + red[1] + red[2] + red[3];
}

__global__ __launch_bounds__(1024) void partial_scan_kernel(int* __restrict__ partials,
                                                            int* __restrict__ row_ptr,
                                                            int nb, int n) {
    __shared__ int sm[1024];
    int t = threadIdx.x;
    int v = (t < nb) ? partials[t] : 0;
    sm[t] = v;
    __syncthreads();
    for (int off = 1; off < 1024; off <<= 1) {
        int u = (t >= off) ? sm[t - off] : 0;
        __syncthreads();
        sm[t] += u;
        __syncthreads();
    }
    if (t < nb) partials[t] = sm[t] - v;
    if (t == 0) row_ptr[n] = sm[1023];
}

__global__ __launch_bounds__(256) void scan_scatter_kernel(const int* __restrict__ counts,
                                                           const int* __restrict__ partials,
                                                           int* __restrict__ row_ptr,
                                                           int* __restrict__ cursor, int n) {
    int t = threadIdx.x;
    int base = blockIdx.x * 1024 + t * 4;
    int c[4];
    int s = 0;
#pragma unroll
    for (int j = 0; j < 4; j++) {
        int i = base + j;
        c[j] = (i < n) ? counts[i] : 0;
        s += c[j];
    }
    __shared__ int sm[256];
    sm[t] = s;
    __syncthreads();
    for (int off = 1; off < 256; off <<= 1) {
        int u = (t >= off) ? sm[t - off] : 0;
        __syncthreads();
        sm[t] += u;
        __syncthreads();
    }
    int run = partials[blockIdx.x] + sm[t] - s;
    int r0 = run, r1 = r0 + c[0], r2 = r1 + c[1], r3 = r2 + c[2];
    if (base + 3 < n) {
        int4 rp = make_int4(r0, r1, r2, r3);
        *reinterpret_cast<int4*>(&row_ptr[base]) = rp;
        *reinterpret_cast<int4*>(&cursor[base])  = rp;
    } else {
        int rr[4] = {r0, r1, r2, r3};
        for (int j = 0; j < 4; j++) {
            int i = base + j;
            if (i < n) { row_ptr[i] = rr[j]; cursor[i] = rr[j]; }
        }
    }
}

__global__ void scatter_kernel(const int* __restrict__ rows, const int* __restrict__ cols,
                               const float* __restrict__ w, int* __restrict__ cursor,
                               int2* __restrict__ ecw, int e) {
    int i = blockIdx.x * blockDim.x + threadIdx.x;
    if (i < e) {
        int p = atomicAdd(&cursor[rows[i]], 1);
        ecw[p] = make_int2(cols[i], __builtin_bit_cast(int, w[i]));
    }
}

// C[n,BN](bf16) = A[n,128](f32) @ B[128,BN](f32). 256 threads, BM=64.
template <int BN, int TN>
__global__ __launch_bounds__(256) void gemm_kernel(const float* __restrict__ A,
                                                   const float* __restrict__ B,
                                                   unsigned short* __restrict__ C, int n) {
    constexpr int BM = 64, BK = 16, K = 128;
    __shared__ float As[BM][BK];
    __shared__ float Bs[BK][BN];
    const int tid = threadIdx.x;
    const int tr = tid >> 5;
    const int tc = tid & 31;
    const int block_row = blockIdx.x * BM;

    float acc[8][TN];
#pragma unroll
    for (int m = 0; m < 8; m++)
#pragma unroll
        for (int j = 0; j < TN; j++) acc[m][j] = 0.f;

    for (int k0 = 0; k0 < K; k0 += BK) {
        {
            int lr = tid >> 2;
            int lk = (tid & 3) << 2;
            int gr = block_row + lr;
            float4 av = make_float4(0.f, 0.f, 0.f, 0.f);
            if (gr < n) av = *reinterpret_cast<const float4*>(&A[(size_t)gr * K + k0 + lk]);
            *reinterpret_cast<float4*>(&As[lr][lk]) = av;
        }
#pragma unroll
        for (int i = 0; i < BN / 64; i++) {
            int idx = tid * (BN / 64) + i;
            int br = idx / (BN / 4);
            int bc = (idx % (BN / 4)) << 2;
            *reinterpret_cast<float4*>(&Bs[br][bc]) =
                *reinterpret_cast<const float4*>(&B[(size_t)(k0 + br) * BN + bc]);
        }
        __syncthreads();
#pragma unroll
        for (int kk = 0; kk < BK; kk++) {
            float a[8];
#pragma unroll
            for (int m = 0; m < 8; m++) a[m] = As[tr * 8 + m][kk];
            float b[TN];
            if constexpr (TN == 4) {
                float4 bv = *reinterpret_cast<const float4*>(&Bs[kk][tc * 4]);
                b[0] = bv.x; b[1] = bv.y; b[2] = bv.z; b[3] = bv.w;
            } else {
                float2 bv = *reinterpret_cast<const float2*>(&Bs[kk][tc * 2]);
                b[0] = bv.x; b[1] = bv.y;
            }
#pragma unroll
            for (int m = 0; m < 8; m++)
#pragma unroll
                for (int j = 0; j < TN; j++) acc[m][j] = fmaf(a[m], b[j], acc[m][j]);
        }
        __syncthreads();
    }
#pragma unroll
    for (int m = 0; m < 8; m++) {
        int gr = block_row + tr * 8 + m;
        if (gr < n) {
            if constexpr (TN == 4) {
                ushort4 v;
                v.x = f2bf(acc[m][0]); v.y = f2bf(acc[m][1]);
                v.z = f2bf(acc[m][2]); v.w = f2bf(acc[m][3]);
                *reinterpret_cast<ushort4*>(&C[(size_t)gr * BN + tc * 4]) = v;
            } else {
                uint32 v = (uint32)f2bf(acc[m][0]) | ((uint32)f2bf(acc[m][1]) << 16);
                *reinterpret_cast<uint32*>(&C[(size_t)gr * BN + tc * 2]) = v;
            }
        }
    }
}

// SpMM d=128: one wave/row, 4 edge-groups x 16 lanes, 16B/lane gather,
// fp32 accum, shfl_xor cross-group reduce, fused bias(+relu).
template <bool RELU>
__global__ __launch_bounds__(256) void spmm128_kernel(const int* __restrict__ row_ptr,
                                                      const int2* __restrict__ ecw,
                                                      const unsigned short* __restrict__ Zb,
                                                      const float* __restrict__ bias,
                                                      float* __restrict__ out, int n) {
    int row = (blockIdx.x * blockDim.x + threadIdx.x) >> 6;
    int lane = threadIdx.x & 63;
    if (row >= n) return;
    int beg = row_ptr[row], end = row_ptr[row + 1];
    const int grp = lane >> 4;
    const int gl  = lane & 15;
    float acc[8] = {0.f, 0.f, 0.f, 0.f, 0.f, 0.f, 0.f, 0.f};
#pragma unroll 2
    for (int k0 = beg; k0 < end; k0 += 4) {
        int k = k0 + grp;
        bool valid = (k < end);
        int kc = valid ? k : (end - 1);
        int2 cw = ecw[kc];
        float w = valid ? __builtin_bit_cast(float, cw.y) : 0.f;
        uint4 z = *reinterpret_cast<const uint4*>(&Zb[((size_t)(uint32)cw.x << 7) + (gl << 3)]);
        acc[0] = fmaf(w, bflo(z.x), acc[0]);
        acc[1] = fmaf(w, bfhi(z.x), acc[1]);
        acc[2] = fmaf(w, bflo(z.y), acc[2]);
        acc[3] = fmaf(w, bfhi(z.y), acc[3]);
        acc[4] = fmaf(w, bflo(z.z), acc[4]);
        acc[5] = fmaf(w, bfhi(z.z), acc[5]);
        acc[6] = fmaf(w, bflo(z.w), acc[6]);
        acc[7] = fmaf(w, bfhi(z.w), acc[7]);
    }
#pragma unroll
    for (int j = 0; j < 8; j++) {
        acc[j] += __shfl_xor(acc[j], 16, 64);
        acc[j] += __shfl_xor(acc[j], 32, 64);
    }
    if (lane < 16) {
        int d0 = gl << 3;
        float4 b0 = *reinterpret_cast<const float4*>(&bias[d0]);
        float4 b1 = *reinterpret_cast<const float4*>(&bias[d0 + 4]);
        float4 v0 = make_float4(acc[0] + b0.x, acc[1] + b0.y, acc[2] + b0.z, acc[3] + b0.w);
        float4 v1 = make_float4(acc[4] + b1.x, acc[5] + b1.y, acc[6] + b1.z, acc[7] + b1.w);
        if constexpr (RELU) {
            v0.x = fmaxf(v0.x, 0.f); v0.y = fmaxf(v0.y, 0.f);
            v0.z = fmaxf(v0.z, 0.f); v0.w = fmaxf(v0.w, 0.f);
            v1.x = fmaxf(v1.x, 0.f); v1.y = fmaxf(v1.y, 0.f);
            v1.z = fmaxf(v1.z, 0.f); v1.w = fmaxf(v1.w, 0.f);
        }
        *reinterpret_cast<float4*>(&out[(size_t)row * 128 + d0])     = v0;
        *reinterpret_cast<float4*>(&out[(size_t)row * 128 + d0 + 4]) = v1;
    }
}

// SpMM d=64: same structure, 8B/lane gather, 4 dims/lane.
__global__ __launch_bounds__(256) void spmm64_kernel(const int* __restrict__ row_ptr,
                                                     const int2* __restrict__ ecw,
                                                     const unsigned short* __restrict__ Zb,
                                                     const float* __restrict__ bias,
                                                     float* __restrict__ out, int n) {
    int row = (blockIdx.x * blockDim.x + threadIdx.x) >> 6;
    int lane = threadIdx.x & 63;
    if (row >= n) return;
    int beg = row_ptr[row], end = row_ptr[row + 1];
    const int grp = lane >> 4;
    const int gl  = lane & 15;
    float acc[4] = {0.f, 0.f, 0.f, 0.f};
#pragma unroll 2
    for (int k0 = beg; k0 < end; k0 += 4) {
        int k = k0 + grp;
        bool valid = (k < end);
        int kc = valid ? k : (end - 1);
        int2 cw = ecw[kc];
        float w = valid ? __builtin_bit_cast(float, cw.y) : 0.f;
        uint2 z = *reinterpret_cast<const uint2*>(&Zb[((size_t)(uint32)cw.x << 6) + (gl << 2)]);
        acc[0] = fmaf(w, bflo(z.x), acc[0]);
        acc[1] = fmaf(w, bfhi(z.x), acc[1]);
        acc[2] = fmaf(w, bflo(z.y), acc[2]);
        acc[3] = fmaf(w, bfhi(z.y), acc[3]);
    }
#pragma unroll
    for (int j = 0; j < 4; j++) {
        acc[j] += __shfl_xor(acc[j], 16, 64);
        acc[j] += __shfl_xor(acc[j], 32, 64);
    }
    if (lane < 16) {
        int d0 = gl << 2;
        float4 b0 = *reinterpret_cast<const float4*>(&bias[d0]);
        float4 v0 = make_float4(acc[0] + b0.x, acc[1] + b0.y, acc[2] + b0.z, acc[3] + b0.w);
        *reinterpret_cast<float4*>(&out[(size_t)row * 64 + d0]) = v0;
    }
}

extern "C" void kernel_launch(void* const* d_in, const int* in_sizes, int n_in,
                              void* d_out, int out_size, void* d_ws, size_t ws_size,
                              hipStream_t stream) {
    const float* X    = (const float*)d_in[0];
    const int*   erow = (const int*)d_in[1];
    const int*   ecol = (const int*)d_in[2];
    const float* ew   = (const float*)d_in[3];
    const float* W1   = (const float*)d_in[4];
    const float* b1   = (const float*)d_in[5];
    const float* W2   = (const float*)d_in[6];
    const float* b2   = (const float*)d_in[7];
    const float* W3   = (const float*)d_in[8];
    const float* b3   = (const float*)d_in[9];
    float* out = (float*)d_out;

    const int n = in_sizes[0] / 128;   // 50000
    const int e = in_sizes[1];         // 800000

    char* p = (char*)d_ws;
    auto alloc = [&](size_t bytes) {
        void* r = (void*)p;
        p += (bytes + 255) & ~(size_t)255;
        return r;
    };
    int*            row_ptr  = (int*)alloc((size_t)(n + 1) * sizeof(int));
    int*            cursor   = (int*)alloc((size_t)n * sizeof(int));
    int*            partials = (int*)alloc(4096 * sizeof(int));
    int2*           ecw      = (int2*)alloc((size_t)e * sizeof(int2));
    unsigned short* Zb       = (unsigned short*)alloc((size_t)n * 128 * sizeof(unsigned short));
    float*          H        = (float*)alloc((size_t)n * 128 * sizeof(float));

    const int eb = (e + 255) / 256;
    const int nb = (n + 1023) / 1024;
    const int gemm_grid = (n + 63) / 64;
    const int spmm_grid = (n + 3) / 4;

    // ---- CSR build ----
    hipMemsetAsync(cursor, 0, (size_t)n * sizeof(int), stream);
    hist_kernel<<<eb, 256, 0, stream>>>(erow, cursor, e);
    partial_sum_kernel<<<nb, 256, 0, stream>>>(cursor, partials, n);
    partial_scan_kernel<<<1, 1024, 0, stream>>>(partials, row_ptr, nb, n);
    scan_scatter_kernel<<<nb, 256, 0, stream>>>(cursor, partials, row_ptr, cursor, n);
    scatter_kernel<<<eb, 256, 0, stream>>>(erow, ecol, ew, cursor, ecw, e);

    // ---- layer 1: Zb = bf16(X @ W1) ; H = relu(A Zb + b1) ----
    gemm_kernel<128, 4><<<gemm_grid, 256, 0, stream>>>(X, W1, Zb, n);
    spmm128_kernel<true><<<spmm_grid, 256, 0, stream>>>(row_ptr, ecw, Zb, b1, H, n);

    // ---- layer 2 ----
    gemm_kernel<128, 4><<<gemm_grid, 256, 0, stream>>>(H, W2, Zb, n);
    spmm128_kernel<true><<<spmm_grid, 256, 0, stream>>>(row_ptr, ecw, Zb, b2, H, n);

    // ---- layer 3: Zb = bf16(H @ W3) (n x 64) ; out = A Zb + b3 ----
    gemm_kernel<64, 2><<<gemm_grid, 256, 0, stream>>>(H, W3, Zb, n);
    spmm64_kernel<<<spmm_grid, 256, 0, stream>>>(row_ptr, ecw, Zb, b3, out, n);
}

// Round 5
// 194.186 us; speedup vs baseline: 2.7832x; 1.3716x over previous
//
#include <hip/hip_runtime.h>

// ---------------------------------------------------------------------------
// GCN: out = A*( relu(A*( relu(A*(X W1)+b1 ) W2)+b2 ) W3 ) + b3
// Reordered (A h) W -> A (h W). CSR build + 3x {GEMM, SpMM}.
// R1: hierarchical scan; R2: Z bf16 (halved gather traffic); R3: SpMM 4x16
//     edge-groups for MLP (latency-bound fix).
// R4a: CSR build via bucket sort (row>>7), LDS counting sorts, coalesced
//      writes -- replaces 800k-random-atomic hist + 52us scatter (64B-line
//      write amp, WRITE_SIZE 52MB for 6.4MB payload).
// R4b: GEMMs -> bf16 MFMA (16x16x32), W pre-transposed to Wt[n][k] bf16,
//      H stored bf16. fp32 accum everywhere; edge weights stay fp32.
// ---------------------------------------------------------------------------

typedef unsigned int uint32;
using bf16x8 = __attribute__((ext_vector_type(8))) short;
using f32x4  = __attribute__((ext_vector_type(4))) float;

static __device__ __forceinline__ unsigned short f2bf(float x) {
    unsigned int u = __builtin_bit_cast(unsigned int, x);
    u += 0x7FFFu + ((u >> 16) & 1u);   // round-to-nearest-even
    return (unsigned short)(u >> 16);
}
static __device__ __forceinline__ float bflo(uint32 u) {
    return __builtin_bit_cast(float, u << 16);
}
static __device__ __forceinline__ float bfhi(uint32 u) {
    return __builtin_bit_cast(float, u & 0xFFFF0000u);
}

// ---------------- CSR build via bucket sort (bucket = row>>7) ----------------

// B1: per-block LDS histogram of buckets, 4096 edges/block.
__global__ __launch_bounds__(256) void bucket_hist_kernel(const int* __restrict__ erow,
                                                          int* __restrict__ bcnt, int e) {
    __shared__ int h[512];
    int t = threadIdx.x;
    h[t] = 0; h[t + 256] = 0;
    __syncthreads();
    int base = blockIdx.x * 4096;
#pragma unroll
    for (int j = 0; j < 4; j++) {
        int idx = base + j * 1024 + t * 4;
        if (idx + 3 < e) {
            int4 r = *reinterpret_cast<const int4*>(&erow[idx]);
            atomicAdd(&h[r.x >> 7], 1); atomicAdd(&h[r.y >> 7], 1);
            atomicAdd(&h[r.z >> 7], 1); atomicAdd(&h[r.w >> 7], 1);
        } else {
            for (int q = 0; q < 4; q++) {
                int i2 = idx + q;
                if (i2 < e) atomicAdd(&h[erow[i2] >> 7], 1);
            }
        }
    }
    __syncthreads();
    if (h[t])       atomicAdd(&bcnt[t], h[t]);
    if (h[t + 256]) atomicAdd(&bcnt[t + 256], h[t + 256]);
}

// B2: scan bucket counts -> bucket_off / bucket_cursor; row_ptr[n] = E.
__global__ __launch_bounds__(512) void bucket_scan_kernel(const int* __restrict__ bcnt,
                                                          int* __restrict__ boff,
                                                          int* __restrict__ bcur,
                                                          int* __restrict__ row_ptr,
                                                          int nb, int n) {
    __shared__ int sm[512];
    int t = threadIdx.x;
    int v = (t < nb) ? bcnt[t] : 0;
    sm[t] = v;
    __syncthreads();
    for (int off = 1; off < 512; off <<= 1) {
        int u = (t >= off) ? sm[t - off] : 0;
        __syncthreads();
        sm[t] += u;
        __syncthreads();
    }
    if (t < nb) { boff[t] = sm[t] - v; bcur[t] = sm[t] - v; }
    if (t == 511) { boff[nb] = sm[511]; row_ptr[n] = sm[511]; }
}

// B3: 4096 edges/block: LDS counting-sort by bucket, one global atomic per
// bucket per block, near-coalesced run writes. Staged as {(b<<23)|(rl<<16)|col, w}.
__global__ __launch_bounds__(256) void bucket_scatter_kernel(const int* __restrict__ erow,
                                                             const int* __restrict__ ecol,
                                                             const float* __restrict__ ew,
                                                             int* __restrict__ bcur,
                                                             int2* __restrict__ ebuf, int e) {
    __shared__ int hist[512];
    __shared__ int psc[256];
    __shared__ int fixup[512];
    __shared__ int2 stage[4096];
    int t = threadIdx.x;
    hist[t] = 0; hist[t + 256] = 0;
    __syncthreads();
    int base = blockIdx.x * 4096;
    int4 rows[4];
#pragma unroll
    for (int j = 0; j < 4; j++) {
        int idx = base + j * 1024 + t * 4;
        int4 r = make_int4(-1, -1, -1, -1);
        if (idx + 3 < e) {
            r = *reinterpret_cast<const int4*>(&erow[idx]);
        } else {
            if (idx < e)     r.x = erow[idx];
            if (idx + 1 < e) r.y = erow[idx + 1];
            if (idx + 2 < e) r.z = erow[idx + 2];
            if (idx + 3 < e) r.w = erow[idx + 3];
        }
        rows[j] = r;
        if (r.x >= 0) atomicAdd(&hist[r.x >> 7], 1);
        if (r.y >= 0) atomicAdd(&hist[r.y >> 7], 1);
        if (r.z >= 0) atomicAdd(&hist[r.z >> 7], 1);
        if (r.w >= 0) atomicAdd(&hist[r.w >> 7], 1);
    }
    __syncthreads();
    int c0 = hist[2 * t], c1 = hist[2 * t + 1];
    int s = c0 + c1;
    psc[t] = s;
    __syncthreads();
    for (int off = 1; off < 256; off <<= 1) {
        int u = (t >= off) ? psc[t - off] : 0;
        __syncthreads();
        psc[t] += u;
        __syncthreads();
    }
    int lo0 = psc[t] - s;
    int lo1 = lo0 + c0;
    if (c0) fixup[2 * t]     = atomicAdd(&bcur[2 * t], c0) - lo0;
    if (c1) fixup[2 * t + 1] = atomicAdd(&bcur[2 * t + 1], c1) - lo1;
    __syncthreads();
    hist[2 * t] = lo0; hist[2 * t + 1] = lo1;
    __syncthreads();
#pragma unroll
    for (int j = 0; j < 4; j++) {
        int idx = base + j * 1024 + t * 4;
        int4 r = rows[j];
        int4 c = make_int4(0, 0, 0, 0);
        float4 w = make_float4(0.f, 0.f, 0.f, 0.f);
        if (idx + 3 < e) {
            c = *reinterpret_cast<const int4*>(&ecol[idx]);
            w = *reinterpret_cast<const float4*>(&ew[idx]);
        } else {
            if (idx < e)     { c.x = ecol[idx];     w.x = ew[idx]; }
            if (idx + 1 < e) { c.y = ecol[idx + 1]; w.y = ew[idx + 1]; }
            if (idx + 2 < e) { c.z = ecol[idx + 2]; w.z = ew[idx + 2]; }
            if (idx + 3 < e) { c.w = ecol[idx + 3]; w.w = ew[idx + 3]; }
        }
        if (r.x >= 0) { int b = r.x >> 7; int sl = atomicAdd(&hist[b], 1);
            stage[sl] = make_int2((b << 23) | ((r.x & 127) << 16) | c.x, __builtin_bit_cast(int, w.x)); }
        if (r.y >= 0) { int b = r.y >> 7; int sl = atomicAdd(&hist[b], 1);
            stage[sl] = make_int2((b << 23) | ((r.y & 127) << 16) | c.y, __builtin_bit_cast(int, w.y)); }
        if (r.z >= 0) { int b = r.z >> 7; int sl = atomicAdd(&hist[b], 1);
            stage[sl] = make_int2((b << 23) | ((r.z & 127) << 16) | c.z, __builtin_bit_cast(int, w.z)); }
        if (r.w >= 0) { int b = r.w >> 7; int sl = atomicAdd(&hist[b], 1);
            stage[sl] = make_int2((b << 23) | ((r.w & 127) << 16) | c.w, __builtin_bit_cast(int, w.w)); }
    }
    __syncthreads();
    int ecnt = min(4096, e - base);
    for (int i = t; i < ecnt; i += 256) {
        int2 v = stage[i];
        int b = ((unsigned)v.x) >> 23;
        ebuf[fixup[b] + i] = v;
    }
}

// B4: one block per bucket: LDS counting-sort by row-local, write row_ptr and
// fully-coalesced CSR segment {col, w}.
__global__ __launch_bounds__(256) void bucket_sort_kernel(const int* __restrict__ boff,
                                                          const int2* __restrict__ ebuf,
                                                          int2* __restrict__ ecsr,
                                                          int* __restrict__ row_ptr, int n) {
    constexpr int MAXB = 3072;
    int b = blockIdx.x;
    int off = boff[b];
    int cnt = min(boff[b + 1] - off, MAXB);
    __shared__ int2 stage[MAXB];
    __shared__ int2 sorted[MAXB];
    __shared__ int rc[128], rs[128], c2[128];
    int t = threadIdx.x;
    if (t < 128) { rc[t] = 0; c2[t] = 0; }
    __syncthreads();
    for (int i = t; i < cnt; i += 256) {
        int2 v = ebuf[off + i];
        stage[i] = v;
        atomicAdd(&rc[(v.x >> 16) & 127], 1);
    }
    __syncthreads();
    if (t < 128) rs[t] = rc[t];
    __syncthreads();
    for (int o = 1; o < 128; o <<= 1) {
        int u = 0;
        if (t < 128 && t >= o) u = rs[t - o];
        __syncthreads();
        if (t < 128) rs[t] += u;
        __syncthreads();
    }
    if (t < 128) {
        int gr = b * 128 + t;
        if (gr < n) row_ptr[gr] = off + rs[t] - rc[t];
    }
    __syncthreads();
    for (int i = t; i < cnt; i += 256) {
        int2 v = stage[i];
        int r = (v.x >> 16) & 127;
        int pos = rs[r] - rc[r] + atomicAdd(&c2[r], 1);
        sorted[pos] = make_int2(v.x & 0xFFFF, v.y);
    }
    __syncthreads();
    for (int i = t; i < cnt; i += 256) ecsr[off + i] = sorted[i];
}

// ---------------- weights: Wt[n][k] bf16 <- W[k][n] f32 ----------------
__global__ __launch_bounds__(256) void transpose_w_kernel(const float* __restrict__ W,
                                                          unsigned short* __restrict__ Wt,
                                                          int N) {
    int gid = blockIdx.x * 256 + threadIdx.x;   // gid = n*128 + k
    int k = gid & 127;
    int nn = gid >> 7;
    Wt[gid] = f2bf(W[k * N + nn]);
}

// ---------------- MFMA GEMM: Zb[n,NOUT] bf16 = A[n,128] @ W ----------------
// 4 waves/block, 16 rows/wave, no LDS. Wt is [NOUT][128] bf16 (k-contiguous).
template <bool AF32, int NOUT>
__global__ __launch_bounds__(256) void gemm_mfma_kernel(const void* __restrict__ Ap,
                                                        const unsigned short* __restrict__ Wt,
                                                        unsigned short* __restrict__ Zb, int n) {
    constexpr int CT = NOUT / 16;
    int wave = threadIdx.x >> 6;
    int lane = threadIdx.x & 63;
    int m0 = blockIdx.x * 64 + wave * 16;
    int r = lane & 15;     // A row / B col
    int g = lane >> 4;     // k-group
    int arow = min(m0 + r, n - 1);
    f32x4 acc[CT] = {};
#pragma unroll
    for (int kt = 0; kt < 4; kt++) {
        int k0 = kt * 32 + g * 8;
        bf16x8 a;
        if constexpr (AF32) {
            const float* A = (const float*)Ap;
            float4 x0 = *reinterpret_cast<const float4*>(&A[(size_t)arow * 128 + k0]);
            float4 x1 = *reinterpret_cast<const float4*>(&A[(size_t)arow * 128 + k0 + 4]);
            a[0] = (short)f2bf(x0.x); a[1] = (short)f2bf(x0.y);
            a[2] = (short)f2bf(x0.z); a[3] = (short)f2bf(x0.w);
            a[4] = (short)f2bf(x1.x); a[5] = (short)f2bf(x1.y);
            a[6] = (short)f2bf(x1.z); a[7] = (short)f2bf(x1.w);
        } else {
            const unsigned short* A = (const unsigned short*)Ap;
            a = *reinterpret_cast<const bf16x8*>(&A[(size_t)arow * 128 + k0]);
        }
#pragma unroll
        for (int c = 0; c < CT; c++) {
            bf16x8 bb = *reinterpret_cast<const bf16x8*>(&Wt[(size_t)(c * 16 + r) * 128 + k0]);
            acc[c] = __builtin_amdgcn_mfma_f32_16x16x32_bf16(a, bb, acc[c], 0, 0, 0);
        }
    }
#pragma unroll
    for (int c = 0; c < CT; c++) {
#pragma unroll
        for (int rr = 0; rr < 4; rr++) {
            int row = m0 + g * 4 + rr;
            if (row < n) Zb[(size_t)row * NOUT + c * 16 + r] = f2bf(acc[c][rr]);
        }
    }
}

// ---------------- SpMM (CSR, 4 edge-groups x 16 lanes) ----------------
// d=128: bf16 out (feeds next GEMM), fused bias+relu.
__global__ __launch_bounds__(256) void spmm128_kernel(const int* __restrict__ row_ptr,
                                                      const int2* __restrict__ ecw,
                                                      const unsigned short* __restrict__ Zb,
                                                      const float* __restrict__ bias,
                                                      unsigned short* __restrict__ Hb, int n) {
    int row = (blockIdx.x * blockDim.x + threadIdx.x) >> 6;
    int lane = threadIdx.x & 63;
    if (row >= n) return;
    int beg = row_ptr[row], end = row_ptr[row + 1];
    const int grp = lane >> 4;
    const int gl  = lane & 15;
    float acc[8] = {0.f, 0.f, 0.f, 0.f, 0.f, 0.f, 0.f, 0.f};
#pragma unroll 2
    for (int k0 = beg; k0 < end; k0 += 4) {
        int k = k0 + grp;
        bool valid = (k < end);
        int kc = valid ? k : (end - 1);
        int2 cw = ecw[kc];
        float w = valid ? __builtin_bit_cast(float, cw.y) : 0.f;
        uint4 z = *reinterpret_cast<const uint4*>(&Zb[((size_t)(uint32)cw.x << 7) + (gl << 3)]);
        acc[0] = fmaf(w, bflo(z.x), acc[0]);
        acc[1] = fmaf(w, bfhi(z.x), acc[1]);
        acc[2] = fmaf(w, bflo(z.y), acc[2]);
        acc[3] = fmaf(w, bfhi(z.y), acc[3]);
        acc[4] = fmaf(w, bflo(z.z), acc[4]);
        acc[5] = fmaf(w, bfhi(z.z), acc[5]);
        acc[6] = fmaf(w, bflo(z.w), acc[6]);
        acc[7] = fmaf(w, bfhi(z.w), acc[7]);
    }
#pragma unroll
    for (int j = 0; j < 8; j++) {
        acc[j] += __shfl_xor(acc[j], 16, 64);
        acc[j] += __shfl_xor(acc[j], 32, 64);
    }
    if (lane < 16) {
        int d0 = gl << 3;
        float4 b0 = *reinterpret_cast<const float4*>(&bias[d0]);
        float4 b1 = *reinterpret_cast<const float4*>(&bias[d0 + 4]);
        float v0 = fmaxf(acc[0] + b0.x, 0.f), v1 = fmaxf(acc[1] + b0.y, 0.f);
        float v2 = fmaxf(acc[2] + b0.z, 0.f), v3 = fmaxf(acc[3] + b0.w, 0.f);
        float v4 = fmaxf(acc[4] + b1.x, 0.f), v5 = fmaxf(acc[5] + b1.y, 0.f);
        float v6 = fmaxf(acc[6] + b1.z, 0.f), v7 = fmaxf(acc[7] + b1.w, 0.f);
        uint4 pk;
        pk.x = (uint32)f2bf(v0) | ((uint32)f2bf(v1) << 16);
        pk.y = (uint32)f2bf(v2) | ((uint32)f2bf(v3) << 16);
        pk.z = (uint32)f2bf(v4) | ((uint32)f2bf(v5) << 16);
        pk.w = (uint32)f2bf(v6) | ((uint32)f2bf(v7) << 16);
        *reinterpret_cast<uint4*>(&Hb[(size_t)row * 128 + d0]) = pk;
    }
}

// d=64: fp32 out (final), bias only.
__global__ __launch_bounds__(256) void spmm64_kernel(const int* __restrict__ row_ptr,
                                                     const int2* __restrict__ ecw,
                                                     const unsigned short* __restrict__ Zb,
                                                     const float* __restrict__ bias,
                                                     float* __restrict__ out, int n) {
    int row = (blockIdx.x * blockDim.x + threadIdx.x) >> 6;
    int lane = threadIdx.x & 63;
    if (row >= n) return;
    int beg = row_ptr[row], end = row_ptr[row + 1];
    const int grp = lane >> 4;
    const int gl  = lane & 15;
    float acc[4] = {0.f, 0.f, 0.f, 0.f};
#pragma unroll 2
    for (int k0 = beg; k0 < end; k0 += 4) {
        int k = k0 + grp;
        bool valid = (k < end);
        int kc = valid ? k : (end - 1);
        int2 cw = ecw[kc];
        float w = valid ? __builtin_bit_cast(float, cw.y) : 0.f;
        uint2 z = *reinterpret_cast<const uint2*>(&Zb[((size_t)(uint32)cw.x << 6) + (gl << 2)]);
        acc[0] = fmaf(w, bflo(z.x), acc[0]);
        acc[1] = fmaf(w, bfhi(z.x), acc[1]);
        acc[2] = fmaf(w, bflo(z.y), acc[2]);
        acc[3] = fmaf(w, bfhi(z.y), acc[3]);
    }
#pragma unroll
    for (int j = 0; j < 4; j++) {
        acc[j] += __shfl_xor(acc[j], 16, 64);
        acc[j] += __shfl_xor(acc[j], 32, 64);
    }
    if (lane < 16) {
        int d0 = gl << 2;
        float4 b0 = *reinterpret_cast<const float4*>(&bias[d0]);
        float4 v0 = make_float4(acc[0] + b0.x, acc[1] + b0.y, acc[2] + b0.z, acc[3] + b0.w);
        *reinterpret_cast<float4*>(&out[(size_t)row * 64 + d0]) = v0;
    }
}

extern "C" void kernel_launch(void* const* d_in, const int* in_sizes, int n_in,
                              void* d_out, int out_size, void* d_ws, size_t ws_size,
                              hipStream_t stream) {
    const float* X    = (const float*)d_in[0];
    const int*   erow = (const int*)d_in[1];
    const int*   ecol = (const int*)d_in[2];
    const float* ew   = (const float*)d_in[3];
    const float* W1   = (const float*)d_in[4];
    const float* b1   = (const float*)d_in[5];
    const float* W2   = (const float*)d_in[6];
    const float* b2   = (const float*)d_in[7];
    const float* W3   = (const float*)d_in[8];
    const float* b3   = (const float*)d_in[9];
    float* out = (float*)d_out;

    const int n = in_sizes[0] / 128;   // 50000
    const int e = in_sizes[1];         // 800000
    const int nb = (n + 127) >> 7;     // 391 buckets

    char* p = (char*)d_ws;
    auto alloc = [&](size_t bytes) {
        void* r = (void*)p;
        p += (bytes + 255) & ~(size_t)255;
        return r;
    };
    int*            row_ptr = (int*)alloc((size_t)(n + 1) * sizeof(int));
    int*            bcnt    = (int*)alloc((size_t)nb * sizeof(int));
    int*            boff    = (int*)alloc((size_t)(nb + 1) * sizeof(int));
    int*            bcur    = (int*)alloc((size_t)nb * sizeof(int));
    int2*           ebuf    = (int2*)alloc((size_t)e * sizeof(int2));
    int2*           ecsr    = (int2*)alloc((size_t)e * sizeof(int2));
    unsigned short* Zb      = (unsigned short*)alloc((size_t)n * 128 * sizeof(unsigned short));
    unsigned short* Hb      = (unsigned short*)alloc((size_t)n * 128 * sizeof(unsigned short));
    unsigned short* Wt1     = (unsigned short*)alloc(128 * 128 * sizeof(unsigned short));
    unsigned short* Wt2     = (unsigned short*)alloc(128 * 128 * sizeof(unsigned short));
    unsigned short* Wt3     = (unsigned short*)alloc(64 * 128 * sizeof(unsigned short));

    const int eb4k = (e + 4095) / 4096;          // 196
    const int gemm_grid = (n + 63) / 64;         // 782
    const int spmm_grid = (n + 3) / 4;           // 12500

    // ---- CSR build (bucket sort) ----
    hipMemsetAsync(bcnt, 0, (size_t)nb * sizeof(int), stream);
    bucket_hist_kernel<<<eb4k, 256, 0, stream>>>(erow, bcnt, e);
    bucket_scan_kernel<<<1, 512, 0, stream>>>(bcnt, boff, bcur, row_ptr, nb, n);
    bucket_scatter_kernel<<<eb4k, 256, 0, stream>>>(erow, ecol, ew, bcur, ebuf, e);
    bucket_sort_kernel<<<nb, 256, 0, stream>>>(boff, ebuf, ecsr, row_ptr, n);

    // ---- weight transposes (f32 -> bf16, [n][k]) ----
    transpose_w_kernel<<<64, 256, 0, stream>>>(W1, Wt1, 128);
    transpose_w_kernel<<<64, 256, 0, stream>>>(W2, Wt2, 128);
    transpose_w_kernel<<<32, 256, 0, stream>>>(W3, Wt3, 64);

    // ---- layer 1: Zb = bf16(X @ W1) ; Hb = bf16(relu(A Zb + b1)) ----
    gemm_mfma_kernel<true, 128><<<gemm_grid, 256, 0, stream>>>(X, Wt1, Zb, n);
    spmm128_kernel<<<spmm_grid, 256, 0, stream>>>(row_ptr, ecsr, Zb, b1, Hb, n);

    // ---- layer 2 ----
    gemm_mfma_kernel<false, 128><<<gemm_grid, 256, 0, stream>>>(Hb, Wt2, Zb, n);
    spmm128_kernel<<<spmm_grid, 256, 0, stream>>>(row_ptr, ecsr, Zb, b2, Hb, n);

    // ---- layer 3: Zb = bf16(Hb @ W3) ; out = A Zb + b3 (fp32) ----
    gemm_mfma_kernel<false, 64><<<gemm_grid, 256, 0, stream>>>(Hb, Wt3, Zb, n);
    spmm64_kernel<<<spmm_grid, 256, 0, stream>>>(row_ptr, ecsr, Zb, b3, out, n);
}

// Round 6
// 180.549 us; speedup vs baseline: 2.9934x; 1.0755x over previous
//
#include <hip/hip_runtime.h>

// ---------------------------------------------------------------------------
// GCN: out = A*( relu(A*( relu(A*(X W1)+b1 ) W2)+b2 ) W3 ) + b3
// Reordered (A h) W -> A (h W). CSR build + 3x {GEMM, SpMM}.
// R1: hierarchical scan; R2: Z bf16; R3: SpMM 4x16 edge-groups;
// R4a: CSR via bucket sort (coalesced); R4b: bf16 MFMA GEMMs.
// R6: SpMM edge/gather decoupling -- one coalesced edge preload into lane
//     registers (<=64 edges/row), shfl broadcast, 4 independent 1KB gathers
//     per body (16 edges) with zero load-chaining. Removes the dependent
//     ecw->gather latency chain that survived R3. Transposes merged.
// ---------------------------------------------------------------------------

typedef unsigned int uint32;
using bf16x8 = __attribute__((ext_vector_type(8))) short;
using f32x4  = __attribute__((ext_vector_type(4))) float;

static __device__ __forceinline__ unsigned short f2bf(float x) {
    unsigned int u = __builtin_bit_cast(unsigned int, x);
    u += 0x7FFFu + ((u >> 16) & 1u);   // round-to-nearest-even
    return (unsigned short)(u >> 16);
}
static __device__ __forceinline__ float bflo(uint32 u) {
    return __builtin_bit_cast(float, u << 16);
}
static __device__ __forceinline__ float bfhi(uint32 u) {
    return __builtin_bit_cast(float, u & 0xFFFF0000u);
}

// ---------------- CSR build via bucket sort (bucket = row>>7) ----------------

__global__ __launch_bounds__(256) void bucket_hist_kernel(const int* __restrict__ erow,
                                                          int* __restrict__ bcnt, int e) {
    __shared__ int h[512];
    int t = threadIdx.x;
    h[t] = 0; h[t + 256] = 0;
    __syncthreads();
    int base = blockIdx.x * 4096;
#pragma unroll
    for (int j = 0; j < 4; j++) {
        int idx = base + j * 1024 + t * 4;
        if (idx + 3 < e) {
            int4 r = *reinterpret_cast<const int4*>(&erow[idx]);
            atomicAdd(&h[r.x >> 7], 1); atomicAdd(&h[r.y >> 7], 1);
            atomicAdd(&h[r.z >> 7], 1); atomicAdd(&h[r.w >> 7], 1);
        } else {
            for (int q = 0; q < 4; q++) {
                int i2 = idx + q;
                if (i2 < e) atomicAdd(&h[erow[i2] >> 7], 1);
            }
        }
    }
    __syncthreads();
    if (h[t])       atomicAdd(&bcnt[t], h[t]);
    if (h[t + 256]) atomicAdd(&bcnt[t + 256], h[t + 256]);
}

__global__ __launch_bounds__(512) void bucket_scan_kernel(const int* __restrict__ bcnt,
                                                          int* __restrict__ boff,
                                                          int* __restrict__ bcur,
                                                          int* __restrict__ row_ptr,
                                                          int nb, int n) {
    __shared__ int sm[512];
    int t = threadIdx.x;
    int v = (t < nb) ? bcnt[t] : 0;
    sm[t] = v;
    __syncthreads();
    for (int off = 1; off < 512; off <<= 1) {
        int u = (t >= off) ? sm[t - off] : 0;
        __syncthreads();
        sm[t] += u;
        __syncthreads();
    }
    if (t < nb) { boff[t] = sm[t] - v; bcur[t] = sm[t] - v; }
    if (t == 511) { boff[nb] = sm[511]; row_ptr[n] = sm[511]; }
}

__global__ __launch_bounds__(256) void bucket_scatter_kernel(const int* __restrict__ erow,
                                                             const int* __restrict__ ecol,
                                                             const float* __restrict__ ew,
                                                             int* __restrict__ bcur,
                                                             int2* __restrict__ ebuf, int e) {
    __shared__ int hist[512];
    __shared__ int psc[256];
    __shared__ int fixup[512];
    __shared__ int2 stage[4096];
    int t = threadIdx.x;
    hist[t] = 0; hist[t + 256] = 0;
    __syncthreads();
    int base = blockIdx.x * 4096;
    int4 rows[4];
#pragma unroll
    for (int j = 0; j < 4; j++) {
        int idx = base + j * 1024 + t * 4;
        int4 r = make_int4(-1, -1, -1, -1);
        if (idx + 3 < e) {
            r = *reinterpret_cast<const int4*>(&erow[idx]);
        } else {
            if (idx < e)     r.x = erow[idx];
            if (idx + 1 < e) r.y = erow[idx + 1];
            if (idx + 2 < e) r.z = erow[idx + 2];
            if (idx + 3 < e) r.w = erow[idx + 3];
        }
        rows[j] = r;
        if (r.x >= 0) atomicAdd(&hist[r.x >> 7], 1);
        if (r.y >= 0) atomicAdd(&hist[r.y >> 7], 1);
        if (r.z >= 0) atomicAdd(&hist[r.z >> 7], 1);
        if (r.w >= 0) atomicAdd(&hist[r.w >> 7], 1);
    }
    __syncthreads();
    int c0 = hist[2 * t], c1 = hist[2 * t + 1];
    int s = c0 + c1;
    psc[t] = s;
    __syncthreads();
    for (int off = 1; off < 256; off <<= 1) {
        int u = (t >= off) ? psc[t - off] : 0;
        __syncthreads();
        psc[t] += u;
        __syncthreads();
    }
    int lo0 = psc[t] - s;
    int lo1 = lo0 + c0;
    if (c0) fixup[2 * t]     = atomicAdd(&bcur[2 * t], c0) - lo0;
    if (c1) fixup[2 * t + 1] = atomicAdd(&bcur[2 * t + 1], c1) - lo1;
    __syncthreads();
    hist[2 * t] = lo0; hist[2 * t + 1] = lo1;
    __syncthreads();
#pragma unroll
    for (int j = 0; j < 4; j++) {
        int idx = base + j * 1024 + t * 4;
        int4 r = rows[j];
        int4 c = make_int4(0, 0, 0, 0);
        float4 w = make_float4(0.f, 0.f, 0.f, 0.f);
        if (idx + 3 < e) {
            c = *reinterpret_cast<const int4*>(&ecol[idx]);
            w = *reinterpret_cast<const float4*>(&ew[idx]);
        } else {
            if (idx < e)     { c.x = ecol[idx];     w.x = ew[idx]; }
            if (idx + 1 < e) { c.y = ecol[idx + 1]; w.y = ew[idx + 1]; }
            if (idx + 2 < e) { c.z = ecol[idx + 2]; w.z = ew[idx + 2]; }
            if (idx + 3 < e) { c.w = ecol[idx + 3]; w.w = ew[idx + 3]; }
        }
        if (r.x >= 0) { int b = r.x >> 7; int sl = atomicAdd(&hist[b], 1);
            stage[sl] = make_int2((b << 23) | ((r.x & 127) << 16) | c.x, __builtin_bit_cast(int, w.x)); }
        if (r.y >= 0) { int b = r.y >> 7; int sl = atomicAdd(&hist[b], 1);
            stage[sl] = make_int2((b << 23) | ((r.y & 127) << 16) | c.y, __builtin_bit_cast(int, w.y)); }
        if (r.z >= 0) { int b = r.z >> 7; int sl = atomicAdd(&hist[b], 1);
            stage[sl] = make_int2((b << 23) | ((r.z & 127) << 16) | c.z, __builtin_bit_cast(int, w.z)); }
        if (r.w >= 0) { int b = r.w >> 7; int sl = atomicAdd(&hist[b], 1);
            stage[sl] = make_int2((b << 23) | ((r.w & 127) << 16) | c.w, __builtin_bit_cast(int, w.w)); }
    }
    __syncthreads();
    int ecnt = min(4096, e - base);
    for (int i = t; i < ecnt; i += 256) {
        int2 v = stage[i];
        int b = ((unsigned)v.x) >> 23;
        ebuf[fixup[b] + i] = v;
    }
}

__global__ __launch_bounds__(256) void bucket_sort_kernel(const int* __restrict__ boff,
                                                          const int2* __restrict__ ebuf,
                                                          int2* __restrict__ ecsr,
                                                          int* __restrict__ row_ptr, int n) {
    constexpr int MAXB = 3072;
    int b = blockIdx.x;
    int off = boff[b];
    int cnt = min(boff[b + 1] - off, MAXB);
    __shared__ int2 stage[MAXB];
    __shared__ int2 sorted[MAXB];
    __shared__ int rc[128], rs[128], c2[128];
    int t = threadIdx.x;
    if (t < 128) { rc[t] = 0; c2[t] = 0; }
    __syncthreads();
    for (int i = t; i < cnt; i += 256) {
        int2 v = ebuf[off + i];
        stage[i] = v;
        atomicAdd(&rc[(v.x >> 16) & 127], 1);
    }
    __syncthreads();
    if (t < 128) rs[t] = rc[t];
    __syncthreads();
    for (int o = 1; o < 128; o <<= 1) {
        int u = 0;
        if (t < 128 && t >= o) u = rs[t - o];
        __syncthreads();
        if (t < 128) rs[t] += u;
        __syncthreads();
    }
    if (t < 128) {
        int gr = b * 128 + t;
        if (gr < n) row_ptr[gr] = off + rs[t] - rc[t];
    }
    __syncthreads();
    for (int i = t; i < cnt; i += 256) {
        int2 v = stage[i];
        int r = (v.x >> 16) & 127;
        int pos = rs[r] - rc[r] + atomicAdd(&c2[r], 1);
        sorted[pos] = make_int2(v.x & 0xFFFF, v.y);
    }
    __syncthreads();
    for (int i = t; i < cnt; i += 256) ecsr[off + i] = sorted[i];
}

// ---------------- weights: Wt[n][k] bf16 <- W[k][n] f32 (all 3 fused) --------
__global__ __launch_bounds__(256) void transpose_w_kernel(const float* __restrict__ W1,
                                                          const float* __restrict__ W2,
                                                          const float* __restrict__ W3,
                                                          unsigned short* __restrict__ Wt1,
                                                          unsigned short* __restrict__ Wt2,
                                                          unsigned short* __restrict__ Wt3) {
    int gid = blockIdx.x * 256 + threadIdx.x;
    if (gid < 16384) {
        Wt1[gid] = f2bf(W1[(gid & 127) * 128 + (gid >> 7)]);
    } else if (gid < 32768) {
        int g = gid - 16384;
        Wt2[g] = f2bf(W2[(g & 127) * 128 + (g >> 7)]);
    } else {
        int g = gid - 32768;   // g = n*128 + k, n<64
        Wt3[g] = f2bf(W3[(g & 127) * 64 + (g >> 7)]);
    }
}

// ---------------- MFMA GEMM: Zb[n,NOUT] bf16 = A[n,128] @ W ----------------
template <bool AF32, int NOUT>
__global__ __launch_bounds__(256) void gemm_mfma_kernel(const void* __restrict__ Ap,
                                                        const unsigned short* __restrict__ Wt,
                                                        unsigned short* __restrict__ Zb, int n) {
    constexpr int CT = NOUT / 16;
    int wave = threadIdx.x >> 6;
    int lane = threadIdx.x & 63;
    int m0 = blockIdx.x * 64 + wave * 16;
    int r = lane & 15;
    int g = lane >> 4;
    int arow = min(m0 + r, n - 1);
    f32x4 acc[CT] = {};
#pragma unroll
    for (int kt = 0; kt < 4; kt++) {
        int k0 = kt * 32 + g * 8;
        bf16x8 a;
        if constexpr (AF32) {
            const float* A = (const float*)Ap;
            float4 x0 = *reinterpret_cast<const float4*>(&A[(size_t)arow * 128 + k0]);
            float4 x1 = *reinterpret_cast<const float4*>(&A[(size_t)arow * 128 + k0 + 4]);
            a[0] = (short)f2bf(x0.x); a[1] = (short)f2bf(x0.y);
            a[2] = (short)f2bf(x0.z); a[3] = (short)f2bf(x0.w);
            a[4] = (short)f2bf(x1.x); a[5] = (short)f2bf(x1.y);
            a[6] = (short)f2bf(x1.z); a[7] = (short)f2bf(x1.w);
        } else {
            const unsigned short* A = (const unsigned short*)Ap;
            a = *reinterpret_cast<const bf16x8*>(&A[(size_t)arow * 128 + k0]);
        }
#pragma unroll
        for (int c = 0; c < CT; c++) {
            bf16x8 bb = *reinterpret_cast<const bf16x8*>(&Wt[(size_t)(c * 16 + r) * 128 + k0]);
            acc[c] = __builtin_amdgcn_mfma_f32_16x16x32_bf16(a, bb, acc[c], 0, 0, 0);
        }
    }
#pragma unroll
    for (int c = 0; c < CT; c++) {
#pragma unroll
        for (int rr = 0; rr < 4; rr++) {
            int row = m0 + g * 4 + rr;
            if (row < n) Zb[(size_t)row * NOUT + c * 16 + r] = f2bf(acc[c][rr]);
        }
    }
}

// ---------------- SpMM d=128: edge/gather decoupled ----------------
// One wave/row. Coalesced preload of <=64 edges into lane regs; per body:
// shfl-broadcast 4 (col,w) pairs x 4 groups -> 16 edges, 4 independent 1KB
// gathers, 32 FMAs. Lanes>=deg carry w=0 + clamped col (self-masking).
__global__ __launch_bounds__(256) void spmm128_kernel(const int* __restrict__ row_ptr,
                                                      const int2* __restrict__ ecw,
                                                      const unsigned short* __restrict__ Zb,
                                                      const float* __restrict__ bias,
                                                      unsigned short* __restrict__ Hb, int n) {
    int row = (blockIdx.x * blockDim.x + threadIdx.x) >> 6;
    int lane = threadIdx.x & 63;
    if (row >= n) return;
    int beg = row_ptr[row], end = row_ptr[row + 1];
    int deg = end - beg;
    const int grp = lane >> 4;
    const int gl  = lane & 15;
    float acc[8] = {0.f, 0.f, 0.f, 0.f, 0.f, 0.f, 0.f, 0.f};
    if (deg > 0) {
        int2 med = ecw[beg + min(lane, deg - 1)];
        float mw = (lane < deg) ? __builtin_bit_cast(float, med.y) : 0.f;
        int  mcol = med.x;
        int nchunk = (min(deg, 64) + 3) >> 2;
        for (int c0 = 0; c0 < nchunk; c0 += 4) {
            int i0 = (c0 + 0) * 4 + grp;
            int i1 = (c0 + 1) * 4 + grp;
            int i2 = (c0 + 2) * 4 + grp;
            int i3 = (c0 + 3) * 4 + grp;
            int col0 = __shfl(mcol, i0, 64); float w0 = __shfl(mw, i0, 64);
            int col1 = __shfl(mcol, i1, 64); float w1 = __shfl(mw, i1, 64);
            int col2 = __shfl(mcol, i2, 64); float w2 = __shfl(mw, i2, 64);
            int col3 = __shfl(mcol, i3, 64); float w3 = __shfl(mw, i3, 64);
            uint4 z0 = *reinterpret_cast<const uint4*>(&Zb[((size_t)(uint32)col0 << 7) + (gl << 3)]);
            uint4 z1 = *reinterpret_cast<const uint4*>(&Zb[((size_t)(uint32)col1 << 7) + (gl << 3)]);
            uint4 z2 = *reinterpret_cast<const uint4*>(&Zb[((size_t)(uint32)col2 << 7) + (gl << 3)]);
            uint4 z3 = *reinterpret_cast<const uint4*>(&Zb[((size_t)(uint32)col3 << 7) + (gl << 3)]);
            acc[0] = fmaf(w0, bflo(z0.x), acc[0]); acc[1] = fmaf(w0, bfhi(z0.x), acc[1]);
            acc[2] = fmaf(w0, bflo(z0.y), acc[2]); acc[3] = fmaf(w0, bfhi(z0.y), acc[3]);
            acc[4] = fmaf(w0, bflo(z0.z), acc[4]); acc[5] = fmaf(w0, bfhi(z0.z), acc[5]);
            acc[6] = fmaf(w0, bflo(z0.w), acc[6]); acc[7] = fmaf(w0, bfhi(z0.w), acc[7]);
            acc[0] = fmaf(w1, bflo(z1.x), acc[0]); acc[1] = fmaf(w1, bfhi(z1.x), acc[1]);
            acc[2] = fmaf(w1, bflo(z1.y), acc[2]); acc[3] = fmaf(w1, bfhi(z1.y), acc[3]);
            acc[4] = fmaf(w1, bflo(z1.z), acc[4]); acc[5] = fmaf(w1, bfhi(z1.z), acc[5]);
            acc[6] = fmaf(w1, bflo(z1.w), acc[6]); acc[7] = fmaf(w1, bfhi(z1.w), acc[7]);
            acc[0] = fmaf(w2, bflo(z2.x), acc[0]); acc[1] = fmaf(w2, bfhi(z2.x), acc[1]);
            acc[2] = fmaf(w2, bflo(z2.y), acc[2]); acc[3] = fmaf(w2, bfhi(z2.y), acc[3]);
            acc[4] = fmaf(w2, bflo(z2.z), acc[4]); acc[5] = fmaf(w2, bfhi(z2.z), acc[5]);
            acc[6] = fmaf(w2, bflo(z2.w), acc[6]); acc[7] = fmaf(w2, bfhi(z2.w), acc[7]);
            acc[0] = fmaf(w3, bflo(z3.x), acc[0]); acc[1] = fmaf(w3, bfhi(z3.x), acc[1]);
            acc[2] = fmaf(w3, bflo(z3.y), acc[2]); acc[3] = fmaf(w3, bfhi(z3.y), acc[3]);
            acc[4] = fmaf(w3, bflo(z3.z), acc[4]); acc[5] = fmaf(w3, bfhi(z3.z), acc[5]);
            acc[6] = fmaf(w3, bflo(z3.w), acc[6]); acc[7] = fmaf(w3, bfhi(z3.w), acc[7]);
        }
        // rare tail: deg > 64
        for (int k0 = beg + 64; k0 < end; k0 += 4) {
            int k = k0 + grp;
            bool valid = (k < end);
            int2 cw = ecw[valid ? k : end - 1];
            float w = valid ? __builtin_bit_cast(float, cw.y) : 0.f;
            uint4 z = *reinterpret_cast<const uint4*>(&Zb[((size_t)(uint32)cw.x << 7) + (gl << 3)]);
            acc[0] = fmaf(w, bflo(z.x), acc[0]); acc[1] = fmaf(w, bfhi(z.x), acc[1]);
            acc[2] = fmaf(w, bflo(z.y), acc[2]); acc[3] = fmaf(w, bfhi(z.y), acc[3]);
            acc[4] = fmaf(w, bflo(z.z), acc[4]); acc[5] = fmaf(w, bfhi(z.z), acc[5]);
            acc[6] = fmaf(w, bflo(z.w), acc[6]); acc[7] = fmaf(w, bfhi(z.w), acc[7]);
        }
    }
#pragma unroll
    for (int j = 0; j < 8; j++) {
        acc[j] += __shfl_xor(acc[j], 16, 64);
        acc[j] += __shfl_xor(acc[j], 32, 64);
    }
    if (lane < 16) {
        int d0 = gl << 3;
        float4 b0 = *reinterpret_cast<const float4*>(&bias[d0]);
        float4 b1 = *reinterpret_cast<const float4*>(&bias[d0 + 4]);
        float v0 = fmaxf(acc[0] + b0.x, 0.f), v1 = fmaxf(acc[1] + b0.y, 0.f);
        float v2 = fmaxf(acc[2] + b0.z, 0.f), v3 = fmaxf(acc[3] + b0.w, 0.f);
        float v4 = fmaxf(acc[4] + b1.x, 0.f), v5 = fmaxf(acc[5] + b1.y, 0.f);
        float v6 = fmaxf(acc[6] + b1.z, 0.f), v7 = fmaxf(acc[7] + b1.w, 0.f);
        uint4 pk;
        pk.x = (uint32)f2bf(v0) | ((uint32)f2bf(v1) << 16);
        pk.y = (uint32)f2bf(v2) | ((uint32)f2bf(v3) << 16);
        pk.z = (uint32)f2bf(v4) | ((uint32)f2bf(v5) << 16);
        pk.w = (uint32)f2bf(v6) | ((uint32)f2bf(v7) << 16);
        *reinterpret_cast<uint4*>(&Hb[(size_t)row * 128 + d0]) = pk;
    }
}

// ---------------- SpMM d=64: same structure, uint2 gathers ----------------
__global__ __launch_bounds__(256) void spmm64_kernel(const int* __restrict__ row_ptr,
                                                     const int2* __restrict__ ecw,
                                                     const unsigned short* __restrict__ Zb,
                                                     const float* __restrict__ bias,
                                                     float* __restrict__ out, int n) {
    int row = (blockIdx.x * blockDim.x + threadIdx.x) >> 6;
    int lane = threadIdx.x & 63;
    if (row >= n) return;
    int beg = row_ptr[row], end = row_ptr[row + 1];
    int deg = end - beg;
    const int grp = lane >> 4;
    const int gl  = lane & 15;
    float acc[4] = {0.f, 0.f, 0.f, 0.f};
    if (deg > 0) {
        int2 med = ecw[beg + min(lane, deg - 1)];
        float mw = (lane < deg) ? __builtin_bit_cast(float, med.y) : 0.f;
        int  mcol = med.x;
        int nchunk = (min(deg, 64) + 3) >> 2;
        for (int c0 = 0; c0 < nchunk; c0 += 4) {
            int i0 = (c0 + 0) * 4 + grp;
            int i1 = (c0 + 1) * 4 + grp;
            int i2 = (c0 + 2) * 4 + grp;
            int i3 = (c0 + 3) * 4 + grp;
            int col0 = __shfl(mcol, i0, 64); float w0 = __shfl(mw, i0, 64);
            int col1 = __shfl(mcol, i1, 64); float w1 = __shfl(mw, i1, 64);
            int col2 = __shfl(mcol, i2, 64); float w2 = __shfl(mw, i2, 64);
            int col3 = __shfl(mcol, i3, 64); float w3 = __shfl(mw, i3, 64);
            uint2 z0 = *reinterpret_cast<const uint2*>(&Zb[((size_t)(uint32)col0 << 6) + (gl << 2)]);
            uint2 z1 = *reinterpret_cast<const uint2*>(&Zb[((size_t)(uint32)col1 << 6) + (gl << 2)]);
            uint2 z2 = *reinterpret_cast<const uint2*>(&Zb[((size_t)(uint32)col2 << 6) + (gl << 2)]);
            uint2 z3 = *reinterpret_cast<const uint2*>(&Zb[((size_t)(uint32)col3 << 6) + (gl << 2)]);
            acc[0] = fmaf(w0, bflo(z0.x), acc[0]); acc[1] = fmaf(w0, bfhi(z0.x), acc[1]);
            acc[2] = fmaf(w0, bflo(z0.y), acc[2]); acc[3] = fmaf(w0, bfhi(z0.y), acc[3]);
            acc[0] = fmaf(w1, bflo(z1.x), acc[0]); acc[1] = fmaf(w1, bfhi(z1.x), acc[1]);
            acc[2] = fmaf(w1, bflo(z1.y), acc[2]); acc[3] = fmaf(w1, bfhi(z1.y), acc[3]);
            acc[0] = fmaf(w2, bflo(z2.x), acc[0]); acc[1] = fmaf(w2, bfhi(z2.x), acc[1]);
            acc[2] = fmaf(w2, bflo(z2.y), acc[2]); acc[3] = fmaf(w2, bfhi(z2.y), acc[3]);
            acc[0] = fmaf(w3, bflo(z3.x), acc[0]); acc[1] = fmaf(w3, bfhi(z3.x), acc[1]);
            acc[2] = fmaf(w3, bflo(z3.y), acc[2]); acc[3] = fmaf(w3, bfhi(z3.y), acc[3]);
        }
        for (int k0 = beg + 64; k0 < end; k0 += 4) {
            int k = k0 + grp;
            bool valid = (k < end);
            int2 cw = ecw[valid ? k : end - 1];
            float w = valid ? __builtin_bit_cast(float, cw.y) : 0.f;
            uint2 z = *reinterpret_cast<const uint2*>(&Zb[((size_t)(uint32)cw.x << 6) + (gl << 2)]);
            acc[0] = fmaf(w, bflo(z.x), acc[0]); acc[1] = fmaf(w, bfhi(z.x), acc[1]);
            acc[2] = fmaf(w, bflo(z.y), acc[2]); acc[3] = fmaf(w, bfhi(z.y), acc[3]);
        }
    }
#pragma unroll
    for (int j = 0; j < 4; j++) {
        acc[j] += __shfl_xor(acc[j], 16, 64);
        acc[j] += __shfl_xor(acc[j], 32, 64);
    }
    if (lane < 16) {
        int d0 = gl << 2;
        float4 b0 = *reinterpret_cast<const float4*>(&bias[d0]);
        float4 v0 = make_float4(acc[0] + b0.x, acc[1] + b0.y, acc[2] + b0.z, acc[3] + b0.w);
        *reinterpret_cast<float4*>(&out[(size_t)row * 64 + d0]) = v0;
    }
}

extern "C" void kernel_launch(void* const* d_in, const int* in_sizes, int n_in,
                              void* d_out, int out_size, void* d_ws, size_t ws_size,
                              hipStream_t stream) {
    const float* X    = (const float*)d_in[0];
    const int*   erow = (const int*)d_in[1];
    const int*   ecol = (const int*)d_in[2];
    const float* ew   = (const float*)d_in[3];
    const float* W1   = (const float*)d_in[4];
    const float* b1   = (const float*)d_in[5];
    const float* W2   = (const float*)d_in[6];
    const float* b2   = (const float*)d_in[7];
    const float* W3   = (const float*)d_in[8];
    const float* b3   = (const float*)d_in[9];
    float* out = (float*)d_out;

    const int n = in_sizes[0] / 128;   // 50000
    const int e = in_sizes[1];         // 800000
    const int nb = (n + 127) >> 7;     // 391 buckets

    char* p = (char*)d_ws;
    auto alloc = [&](size_t bytes) {
        void* r = (void*)p;
        p += (bytes + 255) & ~(size_t)255;
        return r;
    };
    int*            row_ptr = (int*)alloc((size_t)(n + 1) * sizeof(int));
    int*            bcnt    = (int*)alloc((size_t)nb * sizeof(int));
    int*            boff    = (int*)alloc((size_t)(nb + 1) * sizeof(int));
    int*            bcur    = (int*)alloc((size_t)nb * sizeof(int));
    int2*           ebuf    = (int2*)alloc((size_t)e * sizeof(int2));
    int2*           ecsr    = (int2*)alloc((size_t)e * sizeof(int2));
    unsigned short* Zb      = (unsigned short*)alloc((size_t)n * 128 * sizeof(unsigned short));
    unsigned short* Hb      = (unsigned short*)alloc((size_t)n * 128 * sizeof(unsigned short));
    unsigned short* Wt1     = (unsigned short*)alloc(128 * 128 * sizeof(unsigned short));
    unsigned short* Wt2     = (unsigned short*)alloc(128 * 128 * sizeof(unsigned short));
    unsigned short* Wt3     = (unsigned short*)alloc(64 * 128 * sizeof(unsigned short));

    const int eb4k = (e + 4095) / 4096;          // 196
    const int gemm_grid = (n + 63) / 64;         // 782
    const int spmm_grid = (n + 3) / 4;           // 12500

    // ---- CSR build (bucket sort) ----
    hipMemsetAsync(bcnt, 0, (size_t)nb * sizeof(int), stream);
    bucket_hist_kernel<<<eb4k, 256, 0, stream>>>(erow, bcnt, e);
    bucket_scan_kernel<<<1, 512, 0, stream>>>(bcnt, boff, bcur, row_ptr, nb, n);
    bucket_scatter_kernel<<<eb4k, 256, 0, stream>>>(erow, ecol, ew, bcur, ebuf, e);
    bucket_sort_kernel<<<nb, 256, 0, stream>>>(boff, ebuf, ecsr, row_ptr, n);

    // ---- weight transposes (fused) ----
    transpose_w_kernel<<<160, 256, 0, stream>>>(W1, W2, W3, Wt1, Wt2, Wt3);

    // ---- layer 1 ----
    gemm_mfma_kernel<true, 128><<<gemm_grid, 256, 0, stream>>>(X, Wt1, Zb, n);
    spmm128_kernel<<<spmm_grid, 256, 0, stream>>>(row_ptr, ecsr, Zb, b1, Hb, n);

    // ---- layer 2 ----
    gemm_mfma_kernel<false, 128><<<gemm_grid, 256, 0, stream>>>(Hb, Wt2, Zb, n);
    spmm128_kernel<<<spmm_grid, 256, 0, stream>>>(row_ptr, ecsr, Zb, b2, Hb, n);

    // ---- layer 3 ----
    gemm_mfma_kernel<false, 64><<<gemm_grid, 256, 0, stream>>>(Hb, Wt3, Zb, n);
    spmm64_kernel<<<spmm_grid, 256, 0, stream>>>(row_ptr, ecsr, Zb, b3, out, n);
}